// Round 15
// baseline (626.586 us; speedup 1.0000x reference)
//
#include <hip/hip_runtime.h>

typedef unsigned short u16;
using short8_t  = __attribute__((ext_vector_type(8)))  short;
using float16_t = __attribute__((ext_vector_type(16))) float;
using float2v   = __attribute__((ext_vector_type(2)))  float;

#define NKT 260          // K-steps of 16: K = 64*64 + 64 = 4160
#define DEG_CAP 32

__device__ __forceinline__ float bf2f(u16 b) { return __uint_as_float(((unsigned)b) << 16); }
__device__ __forceinline__ u16 f2bf(float f) {
  unsigned u = __float_as_uint(f);
  return (u16)((u + 0x7fffu + ((u >> 16) & 1u)) >> 16);   // RNE
}

union U8 { short8_t s; uint4 v; unsigned u[4]; };

// z = (h * x) truncated to bf16, unpack fused. Bit-identical to prior rounds.
__device__ __forceinline__ short8_t scale8r(U8 xr, float2v h2) {
  U8 out;
  #pragma unroll
  for (int p = 0; p < 4; ++p) {
    float2v r;
    r[0] = __uint_as_float(xr.u[p] << 16);
    r[1] = __uint_as_float(xr.u[p] & 0xffff0000u);
    r = r * h2;
    out.u[p] = __builtin_amdgcn_perm(__float_as_uint(r[1]), __float_as_uint(r[0]), 0x07060302);
  }
  return out.s;
}

// ---------------- mega-setup: affine x4 + pack x4 + all zero-fills, ONE dispatch ----------------
template<int IN>
__device__ __forceinline__ void affine_body(
    const float* __restrict__ Xin, const float* __restrict__ W, const float* __restrict__ Bv,
    u16* __restrict__ Xout, int N, int gid)
{
  int n = gid >> 6, o = gid & 63;
  if (n >= N) return;
  float acc = Bv[o];
  #pragma unroll
  for (int i = 0; i < IN; ++i)
    acc = fmaf(Xin[n * IN + i], W[i * 64 + o], acc);
  Xout[gid] = f2bf(fmaxf(acc, 0.f));
}

__device__ __forceinline__ void bpack_body(
    const float* __restrict__ w2, const float* __restrict__ b2, u16* __restrict__ Bp, int gid)
{
  if (gid >= NKT * 128) return;
  int lane = gid & 63;
  int nt = (gid >> 6) & 1;
  int kt = gid >> 7;
  int o = nt * 32 + (lane & 31);
  int kbase = kt * 16 + (lane >> 5) * 8;
  u16 vals[8];
  #pragma unroll
  for (int j = 0; j < 8; ++j) {
    int k = kbase + j;
    vals[j] = f2bf((k < 4096) ? w2[(k >> 6) * 4096 + (k & 63) * 64 + o]
                              : b2[(k - 4096) * 64 + o]);
  }
  uint4 pack;
  pack.x = (unsigned)vals[0] | ((unsigned)vals[1] << 16);
  pack.y = (unsigned)vals[2] | ((unsigned)vals[3] << 16);
  pack.z = (unsigned)vals[4] | ((unsigned)vals[5] << 16);
  pack.w = (unsigned)vals[6] | ((unsigned)vals[7] << 16);
  *(uint4*)(Bp + (size_t)gid * 8) = pack;
}

__device__ __forceinline__ void rootpack_body(const float* __restrict__ root, u16* __restrict__ Rp, int gid)
{
  if (gid >= 512) return;
  int lane = gid & 63;
  int nt = (gid >> 6) & 1;
  int kt = gid >> 7;
  int o = nt * 32 + (lane & 31);
  int kbase = kt * 16 + (lane >> 5) * 8;
  u16 vals[8];
  #pragma unroll
  for (int j = 0; j < 8; ++j) vals[j] = f2bf(root[(kbase + j) * 64 + o]);
  uint4 pack;
  pack.x = (unsigned)vals[0] | ((unsigned)vals[1] << 16);
  pack.y = (unsigned)vals[2] | ((unsigned)vals[3] << 16);
  pack.z = (unsigned)vals[4] | ((unsigned)vals[5] << 16);
  pack.w = (unsigned)vals[6] | ((unsigned)vals[7] << 16);
  *(uint4*)(Rp + (size_t)gid * 8) = pack;
}

__global__ __launch_bounds__(256) void setup_all_kernel(
    const float* __restrict__ gx, const float* __restrict__ l0w, const float* __restrict__ l0b, u16* __restrict__ xg,
    const float* __restrict__ lgx, const float* __restrict__ llw, const float* __restrict__ llb, u16* __restrict__ xl,
    const float* __restrict__ gea, const float* __restrict__ gw1, const float* __restrict__ gb1, u16* __restrict__ hg,
    const float* __restrict__ lea, const float* __restrict__ lw1, const float* __restrict__ lb1, u16* __restrict__ hl,
    const float* __restrict__ gw2, const float* __restrict__ gb2, u16* __restrict__ bpg,
    const float* __restrict__ lw2, const float* __restrict__ lb2, u16* __restrict__ bpl,
    const float* __restrict__ groot, u16* __restrict__ rpg,
    const float* __restrict__ lroot, u16* __restrict__ rpl,
    int B0, int B1, int B2, int B3, int B4, int B5, int B6, int B7, int B8,
    int NG, int NLG, int EG, int ELG,
    int* __restrict__ zero_ptr, int NZ, float* __restrict__ poolz, int* __restrict__ sync_ctr)
{
  int b = blockIdx.x, t = threadIdx.x;
  if (b < B0)       affine_body<20>(gx, l0w, l0b, xg, NG, b * 256 + t);
  else if (b < B1)  affine_body<5>(lgx, llw, llb, xl, NLG, (b - B0) * 256 + t);
  else if (b < B2)  affine_body<4>(gea, gw1, gb1, hg, EG, (b - B1) * 256 + t);
  else if (b < B3)  affine_body<1>(lea, lw1, lb1, hl, ELG, (b - B2) * 256 + t);
  else if (b < B4) {                       // cnt zero-fill
    int idx = (b - B3) * 256 + t;
    if (idx < NZ) zero_ptr[idx] = 0;
  }
  else if (b < B5)  bpack_body(gw2, gb2, bpg, (b - B4) * 256 + t);
  else if (b < B6)  bpack_body(lw2, lb2, bpl, (b - B5) * 256 + t);
  else if (b < B7)  rootpack_body(groot, rpg, (b - B6) * 256 + t);
  else if (b < B8)  rootpack_body(lroot, rpl, (b - B7) * 256 + t);
  else {                                   // pool buffers + sync counters
    if (t < 128) poolz[t] = 0.f;
    else if (t < 136) sync_ctr[t - 128] = 0;
  }
}

// ---------------- fused bucketed CSR ----------------
__device__ __forceinline__ void hist_body(
    const int* __restrict__ eidx, int* __restrict__ cnt, int* __restrict__ elist, int E, int e)
{
  if (e < E) {
    int tg = eidx[E + e];
    int pos = atomicAdd(cnt + tg, 1);
    if (pos < DEG_CAP) elist[(size_t)tg * DEG_CAP + pos] = e;
  }
}

__global__ __launch_bounds__(256) void hist_kernel(
    const int* __restrict__ eig, int* __restrict__ cg, int* __restrict__ elg, int Eg, int nbg,
    const int* __restrict__ eil, int* __restrict__ cl, int* __restrict__ ell, int El)
{
  int b = blockIdx.x, t = threadIdx.x;
  if (b < nbg) hist_body(eig, cg, elg, Eg, b * 256 + t);
  else         hist_body(eil, cl, ell, El, (b - nbg) * 256 + t);
}

// ---------------- msg = [h (x) x, x] @ B_ext — LDS ring, M=64/wave, 16KB chunks ----------------
// R8 config (best measured: 66us, MfmaUtil 40%). Untouched.
__global__ __launch_bounds__(256, 2) void msg_gemm_kernel(
    const u16* __restrict__ Xg, const u16* __restrict__ Hg, const u16* __restrict__ Bg,
    const int* __restrict__ eig, u16* __restrict__ Mg, int Eg, int nbg,
    const u16* __restrict__ Xl, const u16* __restrict__ Hl, const u16* __restrict__ Bl,
    const int* __restrict__ eil, u16* __restrict__ Ml, int El)
{
  __shared__ __align__(16) u16 sB[4][8192];   // 4 bufs x 16 KB ring

  const int b = blockIdx.x;
  const u16 *X, *Hh, *Bp; const int* eidx; u16* msg; int E, e0;
  if (b < nbg) { X = Xg; Hh = Hg; Bp = Bg; eidx = eig; msg = Mg; E = Eg; e0 = b * 256; }
  else         { X = Xl; Hh = Hl; Bp = Bl; eidx = eil; msg = Ml; E = El; e0 = (b - nbg) * 256; }

  const int t = threadIdx.x;
  const int lane = t & 63;
  const int wid = t >> 6;           // 4 waves x 64 edges = 256 edges/block
  const int ml = lane & 31;
  const int q  = lane >> 5;

  // stage chunks 0..2 immediately (12 DMAs) — overlap the x/h prologue gathers
  #pragma unroll
  for (int c0 = 0; c0 < 3; ++c0) {
    const u16* src = Bp + (size_t)c0 * 8192 + (size_t)wid * 2048 + (size_t)lane * 8;
    u16* dst = &sB[c0][wid * 2048];
    #pragma unroll
    for (int d = 0; d < 4; ++d)
      __builtin_amdgcn_global_load_lds((const __attribute__((address_space(1))) void*)(src + d * 512),
                                       (__attribute__((address_space(3))) void*)(dst + d * 512), 16, 0, 0);
  }

  const int ea  = e0 + wid * 64 + ml;       // tile0 row
  const int eb  = ea + 32;                  // tile1 row
  const int eac = ea < E ? ea : E - 1;
  const int ebc = eb < E ? eb : E - 1;
  const int sa  = eidx[eac], sb = eidx[ebc];

  // x raw bf16 (unpack fused into scale8r): 16 VGPR per tile
  U8 xra[4], xrb[4];
  {
    const u16* xpa = X + (size_t)sa * 64 + q * 8;
    const u16* xpb = X + (size_t)sb * 64 + q * 8;
    #pragma unroll
    for (int s = 0; s < 4; ++s) {
      xra[s].v = *(const uint4*)(xpa + s * 16);
      xrb[s].v = *(const uint4*)(xpb + s * 16);
    }
  }

  // h row streams (both tiles): one uint4 (8 h elems) per group of 4 chunks
  const uint4* ha4 = (const uint4*)(Hh + (size_t)eac * 64);
  const uint4* hb4 = (const uint4*)(Hh + (size_t)ebc * 64);
  uint4 hc0 = ha4[0], hn0 = ha4[1];
  uint4 hc1 = hb4[0], hn1 = hb4[1];

  float16_t acc00, acc01, acc10, acc11;
  #pragma unroll
  for (int i = 0; i < 16; ++i) { acc00[i] = 0.f; acc01[i] = 0.f; acc10[i] = 0.f; acc11[i] = 0.f; }

  // running DMA source pointer (chunk 3 first); bumped +8192 u16 per chunk
  const u16* bsrc = Bp + (size_t)3 * 8192 + (size_t)wid * 2048 + (size_t)lane * 8;

  const short8_t* sb8 = (const short8_t*)&sB[0][0];   // 16B-element view of the ring

  // prologue handoff: drain everything once, then one barrier. Loop never drains again.
  asm volatile("s_waitcnt vmcnt(0)" ::: "memory");
  __builtin_amdgcn_sched_barrier(0);
  __builtin_amdgcn_s_barrier();

  for (int g = 0; g < 8; ++g) {     // group = 4 chunks = 32 kt; hcur word cc -> 2 h-scalars
    #pragma unroll
    for (int cc = 0; cc < 4; ++cc) {
      {   // issue stage(c+3) into ring slot (cc+3)&3 — garbage chunks 33/34 land in Bp slack
        #pragma unroll
        for (int d = 0; d < 4; ++d)
          __builtin_amdgcn_global_load_lds((const __attribute__((address_space(1))) void*)(bsrc + d * 512),
                                           (__attribute__((address_space(3))) void*)(&sB[(cc + 3) & 3][wid * 2048] + d * 512), 16, 0, 0);
        bsrc += 8192;
      }
      unsigned w0 = ((const unsigned*)&hc0)[cc];                 // static index
      unsigned w1 = ((const unsigned*)&hc1)[cc];
      const int sbase = (cc & 3) * 1024;               // short8 index of ring slot (16KB = 1024 short8)
      #pragma unroll
      for (int hh = 0; hh < 2; ++hh) {                 // h-scalar within word: lo then hi
        float2v h20, h21;
        h20[0] = h20[1] = bf2f((u16)(hh ? (w0 >> 16) : (w0 & 0xffffu)));
        h21[0] = h21[1] = bf2f((u16)(hh ? (w1 >> 16) : (w1 & 0xffffu)));
        #pragma unroll
        for (int tt = 0; tt < 4; ++tt) {               // kt = 8c + 4hh + tt
          short8_t b0 = sb8[sbase + (hh * 4 + tt) * 128 + lane];
          short8_t b1 = sb8[sbase + (hh * 4 + tt) * 128 + 64 + lane];
          short8_t a0 = scale8r(xra[tt], h20);
          short8_t a1 = scale8r(xrb[tt], h21);
          acc00 = __builtin_amdgcn_mfma_f32_32x32x16_bf16(a0, b0, acc00, 0, 0, 0);
          acc01 = __builtin_amdgcn_mfma_f32_32x32x16_bf16(a0, b1, acc01, 0, 0, 0);
          acc10 = __builtin_amdgcn_mfma_f32_32x32x16_bf16(a1, b0, acc10, 0, 0, 0);
          acc11 = __builtin_amdgcn_mfma_f32_32x32x16_bf16(a1, b1, acc11, 0, 0, 0);
        }
      }
      // counted handoff: my ds_reads done (free), my stage(c+1) retired; c+2/c+3 in flight
      asm volatile("s_waitcnt lgkmcnt(0)" ::: "memory");
      asm volatile("s_waitcnt vmcnt(8)" ::: "memory");
      __builtin_amdgcn_sched_barrier(0);
      __builtin_amdgcn_s_barrier();
    }
    hc0 = hn0; hc1 = hn1;
    if (g < 6) { hn0 = ha4[g + 2]; hn1 = hb4[g + 2]; }
  }

  // tail: chunk 32 = kt 256..259 (b2 bias rows), A = x exactly (hs=1.0), ring slot 0
  {
    float2v h2; h2[0] = 1.0f; h2[1] = 1.0f;
    #pragma unroll
    for (int tt = 0; tt < 4; ++tt) {
      short8_t b0 = sb8[tt * 128 + lane];
      short8_t b1 = sb8[tt * 128 + 64 + lane];
      short8_t a0 = scale8r(xra[tt], h2);
      short8_t a1 = scale8r(xrb[tt], h2);
      acc00 = __builtin_amdgcn_mfma_f32_32x32x16_bf16(a0, b0, acc00, 0, 0, 0);
      acc01 = __builtin_amdgcn_mfma_f32_32x32x16_bf16(a0, b1, acc01, 0, 0, 0);
      acc10 = __builtin_amdgcn_mfma_f32_32x32x16_bf16(a1, b0, acc10, 0, 0, 0);
      acc11 = __builtin_amdgcn_mfma_f32_32x32x16_bf16(a1, b1, acc11, 0, 0, 0);
    }
  }

  // epilogue: C/D layout col=lane&31, row=(reg&3)+8*(reg>>2)+4*q; bf16 stores, both tiles
  #pragma unroll
  for (int reg = 0; reg < 16; ++reg) {
    int row = (reg & 3) + 8 * (reg >> 2) + 4 * q;
    int e1 = e0 + wid * 64 + row;
    int e2 = e1 + 32;
    if (e1 < E) {
      msg[(size_t)e1 * 64 + ml]      = f2bf(acc00[reg]);
      msg[(size_t)e1 * 64 + 32 + ml] = f2bf(acc01[reg]);
    }
    if (e2 < E) {
      msg[(size_t)e2 * 64 + ml]      = f2bf(acc10[reg]);
      msg[(size_t)e2 * 64 + 32 + ml] = f2bf(acc11[reg]);
    }
  }
}

// ---------------- x_new = relu(x @ root + gather_mean(msg) + bias) — MFMA, fused ----------------
// R15: gather restructured for memory-level parallelism. Old per-row loop had a
// data-dependent bound (cc) -> each row's control flow blocked load hoisting for the
// next row (~55us/dispatch inferred). New: phase 1 is BRANCH-FREE masked first-quad
// for all 16 rows (indices sanitized to 0 for j>=cc; x0.0 terms exact); phase 2 is the
// rare residual (cc>4, ~5% of rows) using the ORIGINAL quad+scalar tail from j=4.
// Bit-identical for every cc (quad j=0 == masked quad; +0.0 adds exact).
// Loads use clamped node index (always in-bounds); only stores are guarded by nn<N.
__global__ __launch_bounds__(256, 4) void update_kernel(
    const u16* __restrict__ Xig, const u16* __restrict__ Mgg, const int* __restrict__ cg,
    const int* __restrict__ elg, const u16* __restrict__ rpg, const float* __restrict__ bg,
    u16* __restrict__ Xog, int Ng, int nbg,
    const u16* __restrict__ Xil, const u16* __restrict__ Mgl, const int* __restrict__ cl,
    const int* __restrict__ ell, const u16* __restrict__ rpl, const float* __restrict__ bl,
    u16* __restrict__ Xol, int Nl)
{
  const int b = blockIdx.x;
  const u16 *Xin, *rootp, *msg; const float *bias; const int *cnt, *elist;
  u16* Xout; int N, n0;
  if (b < nbg) { Xin=Xig; msg=Mgg; cnt=cg; elist=elg; rootp=rpg; bias=bg; Xout=Xog; N=Ng; n0=b*128; }
  else         { Xin=Xil; msg=Mgl; cnt=cl; elist=ell; rootp=rpl; bias=bl; Xout=Xol; N=Nl; n0=(b-nbg)*128; }

  const int t = threadIdx.x;
  const int lane = t & 63;
  const int wid = t >> 6;
  const int ml = lane & 31;
  const int q  = lane >> 5;
  const int nbase = n0 + wid * 32;

  const int na = nbase + ml;
  const int nac = na < N ? na : N - 1;

  U8 xr[4];
  {
    const u16* xp = Xin + (size_t)nac * 64 + q * 8;
    #pragma unroll
    for (int s = 0; s < 4; ++s) xr[s].v = *(const uint4*)(xp + s * 16);
  }
  U8 rp[8];
  {
    const uint4* rpv = (const uint4*)rootp;
    #pragma unroll
    for (int i = 0; i < 8; ++i) rp[i].v = rpv[i * 64 + lane];
  }
  const float bias0 = bias[ml], bias1 = bias[32 + ml];

  float16_t acc0, acc1;
  #pragma unroll
  for (int i = 0; i < 16; ++i) { acc0[i] = 0.f; acc1[i] = 0.f; }
  #pragma unroll
  for (int kt = 0; kt < 4; ++kt) {
    acc0 = __builtin_amdgcn_mfma_f32_32x32x16_bf16(xr[kt].s, rp[kt * 2 + 0].s, acc0, 0, 0, 0);
    acc1 = __builtin_amdgcn_mfma_f32_32x32x16_bf16(xr[kt].s, rp[kt * 2 + 1].s, acc1, 0, 0, 0);
  }

  // phase 0: clamped node ids + cnt loads (branch-free)
  int nns[16], ccs[16];
  #pragma unroll
  for (int reg = 0; reg < 16; ++reg) {
    int row = (reg & 3) + 8 * (reg >> 2) + 4 * q;
    int nn = nbase + row;
    nns[reg] = nn;
    int nnc = nn < N ? nn : N - 1;
    int c = cnt[nnc];
    ccs[reg] = c < DEG_CAP ? c : DEG_CAP;
  }

  // phase 1: branch-free masked first-quad for ALL 16 rows (massive load batch)
  float a0s[16], a1s[16];
  #pragma unroll
  for (int reg = 0; reg < 16; ++reg) {
    int nnc = nns[reg] < N ? nns[reg] : N - 1;
    int cc = ccs[reg];
    const int* ep = elist + (size_t)nnc * DEG_CAP;
    int e0i = ep[0], e1i = ep[1], e2i = ep[2], e3i = ep[3];
    e0i = (cc > 0) ? e0i : 0;
    e1i = (cc > 1) ? e1i : 0;
    e2i = (cc > 2) ? e2i : 0;
    e3i = (cc > 3) ? e3i : 0;
    float k0 = (cc > 0) ? 1.f : 0.f, k1 = (cc > 1) ? 1.f : 0.f;
    float k2 = (cc > 2) ? 1.f : 0.f, k3 = (cc > 3) ? 1.f : 0.f;
    float m00 = bf2f(msg[(size_t)e0i * 64 + ml]) * k0, m01 = bf2f(msg[(size_t)e0i * 64 + 32 + ml]) * k0;
    float m10 = bf2f(msg[(size_t)e1i * 64 + ml]) * k1, m11 = bf2f(msg[(size_t)e1i * 64 + 32 + ml]) * k1;
    float m20 = bf2f(msg[(size_t)e2i * 64 + ml]) * k2, m21 = bf2f(msg[(size_t)e2i * 64 + 32 + ml]) * k2;
    float m30 = bf2f(msg[(size_t)e3i * 64 + ml]) * k3, m31 = bf2f(msg[(size_t)e3i * 64 + 32 + ml]) * k3;
    a0s[reg] = ((m00 + m10) + m20) + m30;
    a1s[reg] = ((m01 + m11) + m21) + m31;
  }

  // phase 2: rare residual (cc > 4) — original quad+scalar tail from j=4 — then store
  #pragma unroll
  for (int reg = 0; reg < 16; ++reg) {
    int nn = nns[reg];
    if (nn < N) {
      int c  = cnt[nn];
      int cc = ccs[reg];
      float a0 = a0s[reg], a1 = a1s[reg];
      if (cc > 4) {
        const int* ep = elist + (size_t)nn * DEG_CAP;
        int j = 4;
        for (; j + 4 <= cc; j += 4) {
          int f0 = ep[j], f1 = ep[j + 1], f2 = ep[j + 2], f3 = ep[j + 3];
          u16 m00 = msg[(size_t)f0 * 64 + ml], m01 = msg[(size_t)f0 * 64 + 32 + ml];
          u16 m10 = msg[(size_t)f1 * 64 + ml], m11 = msg[(size_t)f1 * 64 + 32 + ml];
          u16 m20 = msg[(size_t)f2 * 64 + ml], m21 = msg[(size_t)f2 * 64 + 32 + ml];
          u16 m30 = msg[(size_t)f3 * 64 + ml], m31 = msg[(size_t)f3 * 64 + 32 + ml];
          a0 += bf2f(m00) + bf2f(m10) + bf2f(m20) + bf2f(m30);
          a1 += bf2f(m01) + bf2f(m11) + bf2f(m21) + bf2f(m31);
        }
        for (; j < cc; ++j) {
          int e = ep[j];
          a0 += bf2f(msg[(size_t)e * 64 + ml]);
          a1 += bf2f(msg[(size_t)e * 64 + 32 + ml]);
        }
      }
      float rc = (c > 1) ? (1.0f / (float)c) : 1.0f;
      float o0 = fmaxf(acc0[reg] + a0 * rc + bias0, 0.f);
      float o1 = fmaxf(acc1[reg] + a1 * rc + bias1, 0.f);
      Xout[(size_t)nn * 64 + ml]      = f2bf(o0);
      Xout[(size_t)nn * 64 + 32 + ml] = f2bf(o1);
    }
  }
}

// ---------------- pool + head in ONE dispatch (custom device-scope barriers) ----------------
__device__ __forceinline__ void pool_body(const u16* __restrict__ X, float* __restrict__ out64,
                                          int nchunks, int bid, int t)
{
  __shared__ float red[64];
  if (t < 64) red[t] = 0.f;
  __syncthreads();
  int gid = bid * 256 + t;
  float s[8];
  #pragma unroll
  for (int j = 0; j < 8; ++j) s[j] = 0.f;
  for (int i = gid; i < nchunks; i += 256 * 256) {
    uint4 v = ((const uint4*)X)[i];
    s[0] += bf2f((u16)(v.x & 0xffffu)); s[1] += bf2f((u16)(v.x >> 16));
    s[2] += bf2f((u16)(v.y & 0xffffu)); s[3] += bf2f((u16)(v.y >> 16));
    s[4] += bf2f((u16)(v.z & 0xffffu)); s[5] += bf2f((u16)(v.z >> 16));
    s[6] += bf2f((u16)(v.w & 0xffffu)); s[7] += bf2f((u16)(v.w >> 16));
  }
  int cg = (gid & 7) * 8;
  #pragma unroll
  for (int j = 0; j < 8; ++j) atomicAdd(red + cg + j, s[j]);
  __syncthreads();
  if (t < 64) atomicAdd(out64 + t, red[t]);
}

// block-level barrier among the 24 head blocks: monotonic counter, device-scope.
__device__ __forceinline__ void head_bar(int* ctr, int target, int t)
{
  __syncthreads();                         // all stores of this block issued
  if (t == 0) {
    __threadfence();                       // release: flush to coherent point
    atomicAdd(ctr, 1);
    while (atomicAdd(ctr, 0) < target)     // device-scope RMW read
      __builtin_amdgcn_s_sleep(2);
    __threadfence();                       // acquire: invalidate stale caches
  }
  __syncthreads();
}

__global__ __launch_bounds__(256) void pool_head_kernel(
    const u16* __restrict__ Xg, float* __restrict__ og, int ncg,
    const u16* __restrict__ Xl, float* __restrict__ ol, int ncl,
    const float* __restrict__ adduct,
    const float* __restrict__ bw, const float* __restrict__ bb,
    const float* __restrict__ l1w, const float* __restrict__ l1b,
    const float* __restrict__ l2w, const float* __restrict__ l2b,
    float* __restrict__ h0, float* __restrict__ h1,
    int* __restrict__ sync_ctr, float* __restrict__ out)
{
  const int b = blockIdx.x, t = threadIdx.x;

  if (b < 512) {          // pool producers (bit-identical to R12 pool)
    if (b < 256) pool_body(Xg, og, ncg, b, t);
    else         pool_body(Xl, ol, ncl, b - 256, t);
    __syncthreads();
    if (t == 0) { __threadfence(); atomicAdd(&sync_ctr[0], 1); }
    return;
  }

  // head blocks hb = 0..23 — wait for all 512 pool blocks
  const int hb = b - 512;
  if (t == 0) {
    while (atomicAdd(&sync_ctr[0], 0) < 512) __builtin_amdgcn_s_sleep(8);
    __threadfence();
  }
  __syncthreads();

  __shared__ float red[16][17];
  __shared__ float wred[4];
  const int ol_ = t & 15, ig = t >> 4;
  const int o = hb * 16 + ol_;

  // bott: relu(bb + [pool_g|pool_l|adduct] @ bw)  (identical order to gemv_bott)
  {
    float s = 0.f;
    for (int i = ig; i < 131; i += 16) {
      float v = (i < 64) ? og[i] : (i < 128 ? ol[i - 64] : adduct[i - 128]);
      s = fmaf(v, bw[i * 384 + o], s);
    }
    red[ig][ol_] = s;
    __syncthreads();
    if (t < 16) {
      int oo = hb * 16 + t;
      float acc = bb[oo];
      #pragma unroll
      for (int g = 0; g < 16; ++g) acc += red[g][t];
      h0[oo] = fmaxf(acc, 0.f);
    }
  }
  head_bar(&sync_ctr[1], 24, t);

  // 6x lin1 (identical arithmetic to gemv_relu_kernel)
  float* ua = h0; float* ub = h1;
  for (int L = 0; L < 6; ++L) {
    float s = 0.f;
    for (int i = ig; i < 384; i += 16)
      s = fmaf(ua[i], l1w[i * 384 + o], s);
    red[ig][ol_] = s;
    __syncthreads();
    if (t < 16) {
      int oo = hb * 16 + t;
      float acc = l1b[oo];
      #pragma unroll
      for (int g = 0; g < 16; ++g) acc += red[g][t];
      ub[oo] = fmaxf(acc, 0.f);
    }
    head_bar(&sync_ctr[1], 24 * (L + 2), t);
    float* tmp = ua; ua = ub; ub = tmp;
  }

  // final: u @ l2w + l2b -> scalar (head block 0; 256 threads, validated in R13)
  if (hb == 0) {
    float p = ua[t] * l2w[t];
    if (t < 128) p += ua[t + 256] * l2w[t + 256];
    #pragma unroll
    for (int off = 32; off > 0; off >>= 1) p += __shfl_down(p, off);
    if ((t & 63) == 0) wred[t >> 6] = p;
    __syncthreads();
    if (t == 0) {
      float s = l2b[0];
      #pragma unroll
      for (int i = 0; i < 4; ++i) s += wred[i];
      out[0] = s;
    }
  }
}

extern "C" void kernel_launch(void* const* d_in, const int* in_sizes, int n_in,
                              void* d_out, int out_size, void* d_ws, size_t ws_size,
                              hipStream_t stream)
{
  const int NG = 30000, EG = 60000, NLG = 60000, ELG = 60000;

  const float* gx      = (const float*)d_in[0];
  const int*   g_ei    = (const int*)  d_in[1];
  const float* g_ea    = (const float*)d_in[2];
  const float* lgx     = (const float*)d_in[3];
  const int*   lg_ei   = (const int*)  d_in[4];
  const float* lg_ea   = (const float*)d_in[5];
  const float* adduct  = (const float*)d_in[6];
  const float* lin0_w  = (const float*)d_in[7];
  const float* lin0_b  = (const float*)d_in[8];
  const float* g_w1    = (const float*)d_in[9];
  const float* g_b1    = (const float*)d_in[10];
  const float* g_w2    = (const float*)d_in[11];
  const float* g_b2    = (const float*)d_in[12];
  const float* g_root  = (const float*)d_in[13];
  const float* g_bias  = (const float*)d_in[14];
  const float* l0lg_w  = (const float*)d_in[15];
  const float* l0lg_b  = (const float*)d_in[16];
  const float* lg_w1   = (const float*)d_in[17];
  const float* lg_b1   = (const float*)d_in[18];
  const float* lg_w2   = (const float*)d_in[19];
  const float* lg_b2   = (const float*)d_in[20];
  const float* lg_root = (const float*)d_in[21];
  const float* lg_bias = (const float*)d_in[22];
  const float* bott_w  = (const float*)d_in[23];
  const float* bott_b  = (const float*)d_in[24];
  const float* lin1_w  = (const float*)d_in[25];
  const float* lin1_b  = (const float*)d_in[26];
  const float* lin2_w  = (const float*)d_in[27];
  const float* lin2_b  = (const float*)d_in[28];

  char* p = (char*)d_ws;
  auto alloc = [&](size_t bytes) { char* r = p; p += (bytes + 255) & ~(size_t)255; return r; };
  u16*   xg_a   = (u16*)  alloc((size_t)NG  * 64 * 2);
  u16*   xg_b   = (u16*)  alloc((size_t)NG  * 64 * 2);
  u16*   xl_a   = (u16*)  alloc((size_t)NLG * 64 * 2);
  u16*   xl_b   = (u16*)  alloc((size_t)NLG * 64 * 2);
  u16*   h_g    = (u16*)  alloc((size_t)EG  * 64 * 2);
  u16*   h_l    = (u16*)  alloc((size_t)ELG * 64 * 2);
  u16*   bp_g   = (u16*)  alloc((size_t)NKT * 128 * 8 * 2 + 49152);  // slack: 16KB chunks stage up to chunk 34
  u16*   bp_l   = (u16*)  alloc((size_t)NKT * 128 * 8 * 2 + 49152);
  u16*   rp_g   = (u16*)  alloc(512 * 8 * 2);
  u16*   rp_l   = (u16*)  alloc(512 * 8 * 2);
  u16*   msg_g  = (u16*)  alloc((size_t)EG  * 64 * 2);   // bf16 msg
  u16*   msg_l  = (u16*)  alloc((size_t)ELG * 64 * 2);
  int*   cnt_g  = (int*)  alloc((size_t)NG  * 4);   // cnt_g/cnt_l adjacent: single zero-fill span
  int*   cnt_l  = (int*)  alloc((size_t)NLG * 4);
  int*   el_g   = (int*)  alloc((size_t)NG  * DEG_CAP * 4);
  int*   el_l   = (int*)  alloc((size_t)NLG * DEG_CAP * 4);
  float* pool_g = (float*)alloc(64 * 4);            // pools adjacent: zeroed in setup
  float* pool_l = (float*)alloc(64 * 4);
  float* h0     = (float*)alloc(384 * 4);
  float* h1     = (float*)alloc(384 * 4);
  int*   sctr   = (int*)  alloc(8 * 4);             // [0]=pool_done, [1]=layer barrier

  // ---- mega-setup: affine x4 + cnt zero + pack x4 + pool/sync zero (1 dispatch) ----
  const int B0 = NG * 64 / 256, B1 = B0 + NLG * 64 / 256, B2 = B1 + EG * 64 / 256;
  const int B3 = B2 + ELG * 64 / 256;
  const int NZ = (int)(((size_t)((char*)cnt_l - (char*)cnt_g)) / 4) + NLG;  // span incl. align pad
  const int B4 = B3 + (NZ + 255) / 256;
  const int B5 = B4 + 130, B6 = B5 + 130, B7 = B6 + 2, B8 = B7 + 2;
  setup_all_kernel<<<B8 + 1, 256, 0, stream>>>(
      gx, lin0_w, lin0_b, xg_a, lgx, l0lg_w, l0lg_b, xl_a,
      g_ea, g_w1, g_b1, h_g, lg_ea, lg_w1, lg_b1, h_l,
      g_w2, g_b2, bp_g, lg_w2, lg_b2, bp_l, g_root, rp_g, lg_root, rp_l,
      B0, B1, B2, B3, B4, B5, B6, B7, B8,
      NG, NLG, EG, ELG, cnt_g, NZ, pool_g, sctr);
  const int nhg = (EG + 255) / 256, nhl = (ELG + 255) / 256;
  hist_kernel<<<nhg + nhl, 256, 0, stream>>>(g_ei, cnt_g, el_g, EG, nhg, lg_ei, cnt_l, el_l, ELG);

  // ---- fused 3-iteration loop (256 edges/block, 4 waves x 64 edges, 16KB-chunk LDS ring) ----
  const int nbg_m = (EG + 255) / 256, nbl_m = (ELG + 255) / 256;
  const int nbg_u = (NG + 127) / 128, nbl_u = (NLG + 127) / 128;
  u16 *xgc = xg_a, *xgn = xg_b, *xlc = xl_a, *xln = xl_b;
  for (int it = 0; it < 3; ++it) {
    msg_gemm_kernel<<<nbg_m + nbl_m, 256, 0, stream>>>(
        xgc, h_g, bp_g, g_ei, msg_g, EG, nbg_m,
        xlc, h_l, bp_l, lg_ei, msg_l, ELG);
    update_kernel<<<nbg_u + nbl_u, 256, 0, stream>>>(
        xgc, msg_g, cnt_g, el_g, rp_g, g_bias, xgn, NG, nbg_u,
        xlc, msg_l, cnt_l, el_l, rp_l, lg_bias, xln, NLG);
    u16* tmp = xgc; xgc = xgn; xgn = tmp;
    tmp = xlc; xlc = xln; xln = tmp;
  }

  // ---- pool + head: one dispatch (512 pool blocks + 24 head blocks, spin barriers) ----
  pool_head_kernel<<<536, 256, 0, stream>>>(
      xgc, pool_g, NG * 8, xlc, pool_l, NLG * 8,
      adduct, bott_w, bott_b, lin1_w, lin1_b, lin2_w, lin2_b,
      h0, h1, sctr, (float*)d_out);
}

// Round 16
// 443.504 us; speedup vs baseline: 1.4128x; 1.4128x over previous
//
#include <hip/hip_runtime.h>

typedef unsigned short u16;
using short8_t  = __attribute__((ext_vector_type(8)))  short;
using float16_t = __attribute__((ext_vector_type(16))) float;
using float2v   = __attribute__((ext_vector_type(2)))  float;

#define NKT 260          // K-steps of 16: K = 64*64 + 64 = 4160
#define DEG_CAP 32

__device__ __forceinline__ float bf2f(u16 b) { return __uint_as_float(((unsigned)b) << 16); }
__device__ __forceinline__ u16 f2bf(float f) {
  unsigned u = __float_as_uint(f);
  return (u16)((u + 0x7fffu + ((u >> 16) & 1u)) >> 16);   // RNE
}

union U8 { short8_t s; uint4 v; unsigned u[4]; };

// z = (h * x) truncated to bf16, unpack fused. Bit-identical to prior rounds.
__device__ __forceinline__ short8_t scale8r(U8 xr, float2v h2) {
  U8 out;
  #pragma unroll
  for (int p = 0; p < 4; ++p) {
    float2v r;
    r[0] = __uint_as_float(xr.u[p] << 16);
    r[1] = __uint_as_float(xr.u[p] & 0xffff0000u);
    r = r * h2;
    out.u[p] = __builtin_amdgcn_perm(__float_as_uint(r[1]), __float_as_uint(r[0]), 0x07060302);
  }
  return out.s;
}

// ---------------- mega-setup: affine x4 + pack x4 + all zero-fills, ONE dispatch ----------------
template<int IN>
__device__ __forceinline__ void affine_body(
    const float* __restrict__ Xin, const float* __restrict__ W, const float* __restrict__ Bv,
    u16* __restrict__ Xout, int N, int gid)
{
  int n = gid >> 6, o = gid & 63;
  if (n >= N) return;
  float acc = Bv[o];
  #pragma unroll
  for (int i = 0; i < IN; ++i)
    acc = fmaf(Xin[n * IN + i], W[i * 64 + o], acc);
  Xout[gid] = f2bf(fmaxf(acc, 0.f));
}

__device__ __forceinline__ void bpack_body(
    const float* __restrict__ w2, const float* __restrict__ b2, u16* __restrict__ Bp, int gid)
{
  if (gid >= NKT * 128) return;
  int lane = gid & 63;
  int nt = (gid >> 6) & 1;
  int kt = gid >> 7;
  int o = nt * 32 + (lane & 31);
  int kbase = kt * 16 + (lane >> 5) * 8;
  u16 vals[8];
  #pragma unroll
  for (int j = 0; j < 8; ++j) {
    int k = kbase + j;
    vals[j] = f2bf((k < 4096) ? w2[(k >> 6) * 4096 + (k & 63) * 64 + o]
                              : b2[(k - 4096) * 64 + o]);
  }
  uint4 pack;
  pack.x = (unsigned)vals[0] | ((unsigned)vals[1] << 16);
  pack.y = (unsigned)vals[2] | ((unsigned)vals[3] << 16);
  pack.z = (unsigned)vals[4] | ((unsigned)vals[5] << 16);
  pack.w = (unsigned)vals[6] | ((unsigned)vals[7] << 16);
  *(uint4*)(Bp + (size_t)gid * 8) = pack;
}

__device__ __forceinline__ void rootpack_body(const float* __restrict__ root, u16* __restrict__ Rp, int gid)
{
  if (gid >= 512) return;
  int lane = gid & 63;
  int nt = (gid >> 6) & 1;
  int kt = gid >> 7;
  int o = nt * 32 + (lane & 31);
  int kbase = kt * 16 + (lane >> 5) * 8;
  u16 vals[8];
  #pragma unroll
  for (int j = 0; j < 8; ++j) vals[j] = f2bf(root[(kbase + j) * 64 + o]);
  uint4 pack;
  pack.x = (unsigned)vals[0] | ((unsigned)vals[1] << 16);
  pack.y = (unsigned)vals[2] | ((unsigned)vals[3] << 16);
  pack.z = (unsigned)vals[4] | ((unsigned)vals[5] << 16);
  pack.w = (unsigned)vals[6] | ((unsigned)vals[7] << 16);
  *(uint4*)(Rp + (size_t)gid * 8) = pack;
}

__global__ __launch_bounds__(256) void setup_all_kernel(
    const float* __restrict__ gx, const float* __restrict__ l0w, const float* __restrict__ l0b, u16* __restrict__ xg,
    const float* __restrict__ lgx, const float* __restrict__ llw, const float* __restrict__ llb, u16* __restrict__ xl,
    const float* __restrict__ gea, const float* __restrict__ gw1, const float* __restrict__ gb1, u16* __restrict__ hg,
    const float* __restrict__ lea, const float* __restrict__ lw1, const float* __restrict__ lb1, u16* __restrict__ hl,
    const float* __restrict__ gw2, const float* __restrict__ gb2, u16* __restrict__ bpg,
    const float* __restrict__ lw2, const float* __restrict__ lb2, u16* __restrict__ bpl,
    const float* __restrict__ groot, u16* __restrict__ rpg,
    const float* __restrict__ lroot, u16* __restrict__ rpl,
    int B0, int B1, int B2, int B3, int B4, int B5, int B6, int B7, int B8,
    int NG, int NLG, int EG, int ELG,
    int* __restrict__ zero_ptr, int NZ, float* __restrict__ poolz, int* __restrict__ sync_ctr)
{
  int b = blockIdx.x, t = threadIdx.x;
  if (b < B0)       affine_body<20>(gx, l0w, l0b, xg, NG, b * 256 + t);
  else if (b < B1)  affine_body<5>(lgx, llw, llb, xl, NLG, (b - B0) * 256 + t);
  else if (b < B2)  affine_body<4>(gea, gw1, gb1, hg, EG, (b - B1) * 256 + t);
  else if (b < B3)  affine_body<1>(lea, lw1, lb1, hl, ELG, (b - B2) * 256 + t);
  else if (b < B4) {                       // cnt zero-fill
    int idx = (b - B3) * 256 + t;
    if (idx < NZ) zero_ptr[idx] = 0;
  }
  else if (b < B5)  bpack_body(gw2, gb2, bpg, (b - B4) * 256 + t);
  else if (b < B6)  bpack_body(lw2, lb2, bpl, (b - B5) * 256 + t);
  else if (b < B7)  rootpack_body(groot, rpg, (b - B6) * 256 + t);
  else if (b < B8)  rootpack_body(lroot, rpl, (b - B7) * 256 + t);
  else {                                   // pool buffers + sync counters
    if (t < 128) poolz[t] = 0.f;
    else if (t < 136) sync_ctr[t - 128] = 0;
  }
}

// ---------------- fused bucketed CSR ----------------
__device__ __forceinline__ void hist_body(
    const int* __restrict__ eidx, int* __restrict__ cnt, int* __restrict__ elist, int E, int e)
{
  if (e < E) {
    int tg = eidx[E + e];
    int pos = atomicAdd(cnt + tg, 1);
    if (pos < DEG_CAP) elist[(size_t)tg * DEG_CAP + pos] = e;
  }
}

__global__ __launch_bounds__(256) void hist_kernel(
    const int* __restrict__ eig, int* __restrict__ cg, int* __restrict__ elg, int Eg, int nbg,
    const int* __restrict__ eil, int* __restrict__ cl, int* __restrict__ ell, int El)
{
  int b = blockIdx.x, t = threadIdx.x;
  if (b < nbg) hist_body(eig, cg, elg, Eg, b * 256 + t);
  else         hist_body(eil, cl, ell, El, (b - nbg) * 256 + t);
}

// ---------------- msg = [h (x) x, x] @ B_ext — LDS ring, M=64/wave, 16KB chunks ----------------
// R8 config (best measured: 66us, MfmaUtil 40%). Untouched.
__global__ __launch_bounds__(256, 2) void msg_gemm_kernel(
    const u16* __restrict__ Xg, const u16* __restrict__ Hg, const u16* __restrict__ Bg,
    const int* __restrict__ eig, u16* __restrict__ Mg, int Eg, int nbg,
    const u16* __restrict__ Xl, const u16* __restrict__ Hl, const u16* __restrict__ Bl,
    const int* __restrict__ eil, u16* __restrict__ Ml, int El)
{
  __shared__ __align__(16) u16 sB[4][8192];   // 4 bufs x 16 KB ring

  const int b = blockIdx.x;
  const u16 *X, *Hh, *Bp; const int* eidx; u16* msg; int E, e0;
  if (b < nbg) { X = Xg; Hh = Hg; Bp = Bg; eidx = eig; msg = Mg; E = Eg; e0 = b * 256; }
  else         { X = Xl; Hh = Hl; Bp = Bl; eidx = eil; msg = Ml; E = El; e0 = (b - nbg) * 256; }

  const int t = threadIdx.x;
  const int lane = t & 63;
  const int wid = t >> 6;           // 4 waves x 64 edges = 256 edges/block
  const int ml = lane & 31;
  const int q  = lane >> 5;

  // stage chunks 0..2 immediately (12 DMAs) — overlap the x/h prologue gathers
  #pragma unroll
  for (int c0 = 0; c0 < 3; ++c0) {
    const u16* src = Bp + (size_t)c0 * 8192 + (size_t)wid * 2048 + (size_t)lane * 8;
    u16* dst = &sB[c0][wid * 2048];
    #pragma unroll
    for (int d = 0; d < 4; ++d)
      __builtin_amdgcn_global_load_lds((const __attribute__((address_space(1))) void*)(src + d * 512),
                                       (__attribute__((address_space(3))) void*)(dst + d * 512), 16, 0, 0);
  }

  const int ea  = e0 + wid * 64 + ml;       // tile0 row
  const int eb  = ea + 32;                  // tile1 row
  const int eac = ea < E ? ea : E - 1;
  const int ebc = eb < E ? eb : E - 1;
  const int sa  = eidx[eac], sb = eidx[ebc];

  // x raw bf16 (unpack fused into scale8r): 16 VGPR per tile
  U8 xra[4], xrb[4];
  {
    const u16* xpa = X + (size_t)sa * 64 + q * 8;
    const u16* xpb = X + (size_t)sb * 64 + q * 8;
    #pragma unroll
    for (int s = 0; s < 4; ++s) {
      xra[s].v = *(const uint4*)(xpa + s * 16);
      xrb[s].v = *(const uint4*)(xpb + s * 16);
    }
  }

  // h row streams (both tiles): one uint4 (8 h elems) per group of 4 chunks
  const uint4* ha4 = (const uint4*)(Hh + (size_t)eac * 64);
  const uint4* hb4 = (const uint4*)(Hh + (size_t)ebc * 64);
  uint4 hc0 = ha4[0], hn0 = ha4[1];
  uint4 hc1 = hb4[0], hn1 = hb4[1];

  float16_t acc00, acc01, acc10, acc11;
  #pragma unroll
  for (int i = 0; i < 16; ++i) { acc00[i] = 0.f; acc01[i] = 0.f; acc10[i] = 0.f; acc11[i] = 0.f; }

  // running DMA source pointer (chunk 3 first); bumped +8192 u16 per chunk
  const u16* bsrc = Bp + (size_t)3 * 8192 + (size_t)wid * 2048 + (size_t)lane * 8;

  const short8_t* sb8 = (const short8_t*)&sB[0][0];   // 16B-element view of the ring

  // prologue handoff: drain everything once, then one barrier. Loop never drains again.
  asm volatile("s_waitcnt vmcnt(0)" ::: "memory");
  __builtin_amdgcn_sched_barrier(0);
  __builtin_amdgcn_s_barrier();

  for (int g = 0; g < 8; ++g) {     // group = 4 chunks = 32 kt; hcur word cc -> 2 h-scalars
    #pragma unroll
    for (int cc = 0; cc < 4; ++cc) {
      {   // issue stage(c+3) into ring slot (cc+3)&3 — garbage chunks 33/34 land in Bp slack
        #pragma unroll
        for (int d = 0; d < 4; ++d)
          __builtin_amdgcn_global_load_lds((const __attribute__((address_space(1))) void*)(bsrc + d * 512),
                                           (__attribute__((address_space(3))) void*)(&sB[(cc + 3) & 3][wid * 2048] + d * 512), 16, 0, 0);
        bsrc += 8192;
      }
      unsigned w0 = ((const unsigned*)&hc0)[cc];                 // static index
      unsigned w1 = ((const unsigned*)&hc1)[cc];
      const int sbase = (cc & 3) * 1024;               // short8 index of ring slot (16KB = 1024 short8)
      #pragma unroll
      for (int hh = 0; hh < 2; ++hh) {                 // h-scalar within word: lo then hi
        float2v h20, h21;
        h20[0] = h20[1] = bf2f((u16)(hh ? (w0 >> 16) : (w0 & 0xffffu)));
        h21[0] = h21[1] = bf2f((u16)(hh ? (w1 >> 16) : (w1 & 0xffffu)));
        #pragma unroll
        for (int tt = 0; tt < 4; ++tt) {               // kt = 8c + 4hh + tt
          short8_t b0 = sb8[sbase + (hh * 4 + tt) * 128 + lane];
          short8_t b1 = sb8[sbase + (hh * 4 + tt) * 128 + 64 + lane];
          short8_t a0 = scale8r(xra[tt], h20);
          short8_t a1 = scale8r(xrb[tt], h21);
          acc00 = __builtin_amdgcn_mfma_f32_32x32x16_bf16(a0, b0, acc00, 0, 0, 0);
          acc01 = __builtin_amdgcn_mfma_f32_32x32x16_bf16(a0, b1, acc01, 0, 0, 0);
          acc10 = __builtin_amdgcn_mfma_f32_32x32x16_bf16(a1, b0, acc10, 0, 0, 0);
          acc11 = __builtin_amdgcn_mfma_f32_32x32x16_bf16(a1, b1, acc11, 0, 0, 0);
        }
      }
      // counted handoff: my ds_reads done (free), my stage(c+1) retired; c+2/c+3 in flight
      asm volatile("s_waitcnt lgkmcnt(0)" ::: "memory");
      asm volatile("s_waitcnt vmcnt(8)" ::: "memory");
      __builtin_amdgcn_sched_barrier(0);
      __builtin_amdgcn_s_barrier();
    }
    hc0 = hn0; hc1 = hn1;
    if (g < 6) { hn0 = ha4[g + 2]; hn1 = hb4[g + 2]; }
  }

  // tail: chunk 32 = kt 256..259 (b2 bias rows), A = x exactly (hs=1.0), ring slot 0
  {
    float2v h2; h2[0] = 1.0f; h2[1] = 1.0f;
    #pragma unroll
    for (int tt = 0; tt < 4; ++tt) {
      short8_t b0 = sb8[tt * 128 + lane];
      short8_t b1 = sb8[tt * 128 + 64 + lane];
      short8_t a0 = scale8r(xra[tt], h2);
      short8_t a1 = scale8r(xrb[tt], h2);
      acc00 = __builtin_amdgcn_mfma_f32_32x32x16_bf16(a0, b0, acc00, 0, 0, 0);
      acc01 = __builtin_amdgcn_mfma_f32_32x32x16_bf16(a0, b1, acc01, 0, 0, 0);
      acc10 = __builtin_amdgcn_mfma_f32_32x32x16_bf16(a1, b0, acc10, 0, 0, 0);
      acc11 = __builtin_amdgcn_mfma_f32_32x32x16_bf16(a1, b1, acc11, 0, 0, 0);
    }
  }

  // epilogue: C/D layout col=lane&31, row=(reg&3)+8*(reg>>2)+4*q; bf16 stores, both tiles
  #pragma unroll
  for (int reg = 0; reg < 16; ++reg) {
    int row = (reg & 3) + 8 * (reg >> 2) + 4 * q;
    int e1 = e0 + wid * 64 + row;
    int e2 = e1 + 32;
    if (e1 < E) {
      msg[(size_t)e1 * 64 + ml]      = f2bf(acc00[reg]);
      msg[(size_t)e1 * 64 + 32 + ml] = f2bf(acc01[reg]);
    }
    if (e2 < E) {
      msg[(size_t)e2 * 64 + ml]      = f2bf(acc10[reg]);
      msg[(size_t)e2 * 64 + 32 + ml] = f2bf(acc11[reg]);
    }
  }
}

// ---------------- x_new = relu(x @ root + gather_mean(msg) + bias) — MFMA, fused ----------------
// R16: R15's MLP restructure re-done spill-proof. R15's 16-row phase arrays (64 regs)
// spilled (WRITE_SIZE 92MB scratch -> 88us). Group-of-4: phase A = branch-free masked
// first-quad for 4 rows (elist row = ONE int4 load; 8 masked msg loads/row -> ~36
// loads in flight), phase B = rare cc>4 residual + store. Live state/group ~16 regs.
// Arithmetic identical to R15 (absmax 0.0 verified); only batching width changes.
__global__ __launch_bounds__(256, 4) void update_kernel(
    const u16* __restrict__ Xig, const u16* __restrict__ Mgg, const int* __restrict__ cg,
    const int* __restrict__ elg, const u16* __restrict__ rpg, const float* __restrict__ bg,
    u16* __restrict__ Xog, int Ng, int nbg,
    const u16* __restrict__ Xil, const u16* __restrict__ Mgl, const int* __restrict__ cl,
    const int* __restrict__ ell, const u16* __restrict__ rpl, const float* __restrict__ bl,
    u16* __restrict__ Xol, int Nl)
{
  const int b = blockIdx.x;
  const u16 *Xin, *rootp, *msg; const float *bias; const int *cnt, *elist;
  u16* Xout; int N, n0;
  if (b < nbg) { Xin=Xig; msg=Mgg; cnt=cg; elist=elg; rootp=rpg; bias=bg; Xout=Xog; N=Ng; n0=b*128; }
  else         { Xin=Xil; msg=Mgl; cnt=cl; elist=ell; rootp=rpl; bias=bl; Xout=Xol; N=Nl; n0=(b-nbg)*128; }

  const int t = threadIdx.x;
  const int lane = t & 63;
  const int wid = t >> 6;
  const int ml = lane & 31;
  const int q  = lane >> 5;
  const int nbase = n0 + wid * 32;

  const int na = nbase + ml;
  const int nac = na < N ? na : N - 1;

  U8 xr[4];
  {
    const u16* xp = Xin + (size_t)nac * 64 + q * 8;
    #pragma unroll
    for (int s = 0; s < 4; ++s) xr[s].v = *(const uint4*)(xp + s * 16);
  }
  U8 rp[8];
  {
    const uint4* rpv = (const uint4*)rootp;
    #pragma unroll
    for (int i = 0; i < 8; ++i) rp[i].v = rpv[i * 64 + lane];
  }
  const float bias0 = bias[ml], bias1 = bias[32 + ml];

  float16_t acc0, acc1;
  #pragma unroll
  for (int i = 0; i < 16; ++i) { acc0[i] = 0.f; acc1[i] = 0.f; }
  #pragma unroll
  for (int kt = 0; kt < 4; ++kt) {
    acc0 = __builtin_amdgcn_mfma_f32_32x32x16_bf16(xr[kt].s, rp[kt * 2 + 0].s, acc0, 0, 0, 0);
    acc1 = __builtin_amdgcn_mfma_f32_32x32x16_bf16(xr[kt].s, rp[kt * 2 + 1].s, acc1, 0, 0, 0);
  }

  #pragma unroll
  for (int grp = 0; grp < 4; ++grp) {
    int nn_[4], cc_[4];
    float a0_[4], a1_[4];
    // phase A: branch-free masked first-quad for 4 rows (batched loads)
    #pragma unroll
    for (int r = 0; r < 4; ++r) {
      const int reg = grp * 4 + r;
      const int row = (reg & 3) + 8 * (reg >> 2) + 4 * q;
      const int nn = nbase + row;
      nn_[r] = nn;
      const int nnc = nn < N ? nn : N - 1;
      int c = cnt[nnc];
      const int cc = c < DEG_CAP ? c : DEG_CAP;
      cc_[r] = cc;
      const int4 e4 = *(const int4*)(elist + (size_t)nnc * DEG_CAP);
      int e0i = (cc > 0) ? e4.x : 0;
      int e1i = (cc > 1) ? e4.y : 0;
      int e2i = (cc > 2) ? e4.z : 0;
      int e3i = (cc > 3) ? e4.w : 0;
      float k0 = (cc > 0) ? 1.f : 0.f, k1 = (cc > 1) ? 1.f : 0.f;
      float k2 = (cc > 2) ? 1.f : 0.f, k3 = (cc > 3) ? 1.f : 0.f;
      float m00 = bf2f(msg[(size_t)e0i * 64 + ml]) * k0, m01 = bf2f(msg[(size_t)e0i * 64 + 32 + ml]) * k0;
      float m10 = bf2f(msg[(size_t)e1i * 64 + ml]) * k1, m11 = bf2f(msg[(size_t)e1i * 64 + 32 + ml]) * k1;
      float m20 = bf2f(msg[(size_t)e2i * 64 + ml]) * k2, m21 = bf2f(msg[(size_t)e2i * 64 + 32 + ml]) * k2;
      float m30 = bf2f(msg[(size_t)e3i * 64 + ml]) * k3, m31 = bf2f(msg[(size_t)e3i * 64 + 32 + ml]) * k3;
      a0_[r] = ((m00 + m10) + m20) + m30;
      a1_[r] = ((m01 + m11) + m21) + m31;
    }
    // phase B: rare residual (cc > 4) — original quad+scalar tail from j=4 — then store
    #pragma unroll
    for (int r = 0; r < 4; ++r) {
      const int reg = grp * 4 + r;
      const int nn = nn_[r];
      if (nn < N) {
        int c  = cnt[nn];
        int cc = cc_[r];
        float a0 = a0_[r], a1 = a1_[r];
        if (cc > 4) {
          const int* ep = elist + (size_t)nn * DEG_CAP;
          int j = 4;
          for (; j + 4 <= cc; j += 4) {
            int f0 = ep[j], f1 = ep[j + 1], f2 = ep[j + 2], f3 = ep[j + 3];
            u16 m00 = msg[(size_t)f0 * 64 + ml], m01 = msg[(size_t)f0 * 64 + 32 + ml];
            u16 m10 = msg[(size_t)f1 * 64 + ml], m11 = msg[(size_t)f1 * 64 + 32 + ml];
            u16 m20 = msg[(size_t)f2 * 64 + ml], m21 = msg[(size_t)f2 * 64 + 32 + ml];
            u16 m30 = msg[(size_t)f3 * 64 + ml], m31 = msg[(size_t)f3 * 64 + 32 + ml];
            a0 += bf2f(m00) + bf2f(m10) + bf2f(m20) + bf2f(m30);
            a1 += bf2f(m01) + bf2f(m11) + bf2f(m21) + bf2f(m31);
          }
          for (; j < cc; ++j) {
            int e = ep[j];
            a0 += bf2f(msg[(size_t)e * 64 + ml]);
            a1 += bf2f(msg[(size_t)e * 64 + 32 + ml]);
          }
        }
        float rc = (c > 1) ? (1.0f / (float)c) : 1.0f;
        float o0 = fmaxf(acc0[reg] + a0 * rc + bias0, 0.f);
        float o1 = fmaxf(acc1[reg] + a1 * rc + bias1, 0.f);
        Xout[(size_t)nn * 64 + ml]      = f2bf(o0);
        Xout[(size_t)nn * 64 + 32 + ml] = f2bf(o1);
      }
    }
  }
}

// ---------------- pool + head in ONE dispatch (custom device-scope barriers) ----------------
__device__ __forceinline__ void pool_body(const u16* __restrict__ X, float* __restrict__ out64,
                                          int nchunks, int bid, int t)
{
  __shared__ float red[64];
  if (t < 64) red[t] = 0.f;
  __syncthreads();
  int gid = bid * 256 + t;
  float s[8];
  #pragma unroll
  for (int j = 0; j < 8; ++j) s[j] = 0.f;
  for (int i = gid; i < nchunks; i += 256 * 256) {
    uint4 v = ((const uint4*)X)[i];
    s[0] += bf2f((u16)(v.x & 0xffffu)); s[1] += bf2f((u16)(v.x >> 16));
    s[2] += bf2f((u16)(v.y & 0xffffu)); s[3] += bf2f((u16)(v.y >> 16));
    s[4] += bf2f((u16)(v.z & 0xffffu)); s[5] += bf2f((u16)(v.z >> 16));
    s[6] += bf2f((u16)(v.w & 0xffffu)); s[7] += bf2f((u16)(v.w >> 16));
  }
  int cg = (gid & 7) * 8;
  #pragma unroll
  for (int j = 0; j < 8; ++j) atomicAdd(red + cg + j, s[j]);
  __syncthreads();
  if (t < 64) atomicAdd(out64 + t, red[t]);
}

// block-level barrier among the 24 head blocks: monotonic counter, device-scope.
__device__ __forceinline__ void head_bar(int* ctr, int target, int t)
{
  __syncthreads();                         // all stores of this block issued
  if (t == 0) {
    __threadfence();                       // release: flush to coherent point
    atomicAdd(ctr, 1);
    while (atomicAdd(ctr, 0) < target)     // device-scope RMW read
      __builtin_amdgcn_s_sleep(2);
    __threadfence();                       // acquire: invalidate stale caches
  }
  __syncthreads();
}

__global__ __launch_bounds__(256) void pool_head_kernel(
    const u16* __restrict__ Xg, float* __restrict__ og, int ncg,
    const u16* __restrict__ Xl, float* __restrict__ ol, int ncl,
    const float* __restrict__ adduct,
    const float* __restrict__ bw, const float* __restrict__ bb,
    const float* __restrict__ l1w, const float* __restrict__ l1b,
    const float* __restrict__ l2w, const float* __restrict__ l2b,
    float* __restrict__ h0, float* __restrict__ h1,
    int* __restrict__ sync_ctr, float* __restrict__ out)
{
  const int b = blockIdx.x, t = threadIdx.x;

  if (b < 512) {          // pool producers (bit-identical to R12 pool)
    if (b < 256) pool_body(Xg, og, ncg, b, t);
    else         pool_body(Xl, ol, ncl, b - 256, t);
    __syncthreads();
    if (t == 0) { __threadfence(); atomicAdd(&sync_ctr[0], 1); }
    return;
  }

  // head blocks hb = 0..23 — wait for all 512 pool blocks
  const int hb = b - 512;
  if (t == 0) {
    while (atomicAdd(&sync_ctr[0], 0) < 512) __builtin_amdgcn_s_sleep(8);
    __threadfence();
  }
  __syncthreads();

  __shared__ float red[16][17];
  __shared__ float wred[4];
  const int ol_ = t & 15, ig = t >> 4;
  const int o = hb * 16 + ol_;

  // bott: relu(bb + [pool_g|pool_l|adduct] @ bw)  (identical order to gemv_bott)
  {
    float s = 0.f;
    for (int i = ig; i < 131; i += 16) {
      float v = (i < 64) ? og[i] : (i < 128 ? ol[i - 64] : adduct[i - 128]);
      s = fmaf(v, bw[i * 384 + o], s);
    }
    red[ig][ol_] = s;
    __syncthreads();
    if (t < 16) {
      int oo = hb * 16 + t;
      float acc = bb[oo];
      #pragma unroll
      for (int g = 0; g < 16; ++g) acc += red[g][t];
      h0[oo] = fmaxf(acc, 0.f);
    }
  }
  head_bar(&sync_ctr[1], 24, t);

  // 6x lin1 (identical arithmetic to gemv_relu_kernel)
  float* ua = h0; float* ub = h1;
  for (int L = 0; L < 6; ++L) {
    float s = 0.f;
    for (int i = ig; i < 384; i += 16)
      s = fmaf(ua[i], l1w[i * 384 + o], s);
    red[ig][ol_] = s;
    __syncthreads();
    if (t < 16) {
      int oo = hb * 16 + t;
      float acc = l1b[oo];
      #pragma unroll
      for (int g = 0; g < 16; ++g) acc += red[g][t];
      ub[oo] = fmaxf(acc, 0.f);
    }
    head_bar(&sync_ctr[1], 24 * (L + 2), t);
    float* tmp = ua; ua = ub; ub = tmp;
  }

  // final: u @ l2w + l2b -> scalar (head block 0; 256 threads, validated in R13)
  if (hb == 0) {
    float p = ua[t] * l2w[t];
    if (t < 128) p += ua[t + 256] * l2w[t + 256];
    #pragma unroll
    for (int off = 32; off > 0; off >>= 1) p += __shfl_down(p, off);
    if ((t & 63) == 0) wred[t >> 6] = p;
    __syncthreads();
    if (t == 0) {
      float s = l2b[0];
      #pragma unroll
      for (int i = 0; i < 4; ++i) s += wred[i];
      out[0] = s;
    }
  }
}

extern "C" void kernel_launch(void* const* d_in, const int* in_sizes, int n_in,
                              void* d_out, int out_size, void* d_ws, size_t ws_size,
                              hipStream_t stream)
{
  const int NG = 30000, EG = 60000, NLG = 60000, ELG = 60000;

  const float* gx      = (const float*)d_in[0];
  const int*   g_ei    = (const int*)  d_in[1];
  const float* g_ea    = (const float*)d_in[2];
  const float* lgx     = (const float*)d_in[3];
  const int*   lg_ei   = (const int*)  d_in[4];
  const float* lg_ea   = (const float*)d_in[5];
  const float* adduct  = (const float*)d_in[6];
  const float* lin0_w  = (const float*)d_in[7];
  const float* lin0_b  = (const float*)d_in[8];
  const float* g_w1    = (const float*)d_in[9];
  const float* g_b1    = (const float*)d_in[10];
  const float* g_w2    = (const float*)d_in[11];
  const float* g_b2    = (const float*)d_in[12];
  const float* g_root  = (const float*)d_in[13];
  const float* g_bias  = (const float*)d_in[14];
  const float* l0lg_w  = (const float*)d_in[15];
  const float* l0lg_b  = (const float*)d_in[16];
  const float* lg_w1   = (const float*)d_in[17];
  const float* lg_b1   = (const float*)d_in[18];
  const float* lg_w2   = (const float*)d_in[19];
  const float* lg_b2   = (const float*)d_in[20];
  const float* lg_root = (const float*)d_in[21];
  const float* lg_bias = (const float*)d_in[22];
  const float* bott_w  = (const float*)d_in[23];
  const float* bott_b  = (const float*)d_in[24];
  const float* lin1_w  = (const float*)d_in[25];
  const float* lin1_b  = (const float*)d_in[26];
  const float* lin2_w  = (const float*)d_in[27];
  const float* lin2_b  = (const float*)d_in[28];

  char* p = (char*)d_ws;
  auto alloc = [&](size_t bytes) { char* r = p; p += (bytes + 255) & ~(size_t)255; return r; };
  u16*   xg_a   = (u16*)  alloc((size_t)NG  * 64 * 2);
  u16*   xg_b   = (u16*)  alloc((size_t)NG  * 64 * 2);
  u16*   xl_a   = (u16*)  alloc((size_t)NLG * 64 * 2);
  u16*   xl_b   = (u16*)  alloc((size_t)NLG * 64 * 2);
  u16*   h_g    = (u16*)  alloc((size_t)EG  * 64 * 2);
  u16*   h_l    = (u16*)  alloc((size_t)ELG * 64 * 2);
  u16*   bp_g   = (u16*)  alloc((size_t)NKT * 128 * 8 * 2 + 49152);  // slack: 16KB chunks stage up to chunk 34
  u16*   bp_l   = (u16*)  alloc((size_t)NKT * 128 * 8 * 2 + 49152);
  u16*   rp_g   = (u16*)  alloc(512 * 8 * 2);
  u16*   rp_l   = (u16*)  alloc(512 * 8 * 2);
  u16*   msg_g  = (u16*)  alloc((size_t)EG  * 64 * 2);   // bf16 msg
  u16*   msg_l  = (u16*)  alloc((size_t)ELG * 64 * 2);
  int*   cnt_g  = (int*)  alloc((size_t)NG  * 4);   // cnt_g/cnt_l adjacent: single zero-fill span
  int*   cnt_l  = (int*)  alloc((size_t)NLG * 4);
  int*   el_g   = (int*)  alloc((size_t)NG  * DEG_CAP * 4);
  int*   el_l   = (int*)  alloc((size_t)NLG * DEG_CAP * 4);
  float* pool_g = (float*)alloc(64 * 4);            // pools adjacent: zeroed in setup
  float* pool_l = (float*)alloc(64 * 4);
  float* h0     = (float*)alloc(384 * 4);
  float* h1     = (float*)alloc(384 * 4);
  int*   sctr   = (int*)  alloc(8 * 4);             // [0]=pool_done, [1]=layer barrier

  // ---- mega-setup: affine x4 + cnt zero + pack x4 + pool/sync zero (1 dispatch) ----
  const int B0 = NG * 64 / 256, B1 = B0 + NLG * 64 / 256, B2 = B1 + EG * 64 / 256;
  const int B3 = B2 + ELG * 64 / 256;
  const int NZ = (int)(((size_t)((char*)cnt_l - (char*)cnt_g)) / 4) + NLG;  // span incl. align pad
  const int B4 = B3 + (NZ + 255) / 256;
  const int B5 = B4 + 130, B6 = B5 + 130, B7 = B6 + 2, B8 = B7 + 2;
  setup_all_kernel<<<B8 + 1, 256, 0, stream>>>(
      gx, lin0_w, lin0_b, xg_a, lgx, l0lg_w, l0lg_b, xl_a,
      g_ea, g_w1, g_b1, h_g, lg_ea, lg_w1, lg_b1, h_l,
      g_w2, g_b2, bp_g, lg_w2, lg_b2, bp_l, g_root, rp_g, lg_root, rp_l,
      B0, B1, B2, B3, B4, B5, B6, B7, B8,
      NG, NLG, EG, ELG, cnt_g, NZ, pool_g, sctr);
  const int nhg = (EG + 255) / 256, nhl = (ELG + 255) / 256;
  hist_kernel<<<nhg + nhl, 256, 0, stream>>>(g_ei, cnt_g, el_g, EG, nhg, lg_ei, cnt_l, el_l, ELG);

  // ---- fused 3-iteration loop (256 edges/block, 4 waves x 64 edges, 16KB-chunk LDS ring) ----
  const int nbg_m = (EG + 255) / 256, nbl_m = (ELG + 255) / 256;
  const int nbg_u = (NG + 127) / 128, nbl_u = (NLG + 127) / 128;
  u16 *xgc = xg_a, *xgn = xg_b, *xlc = xl_a, *xln = xl_b;
  for (int it = 0; it < 3; ++it) {
    msg_gemm_kernel<<<nbg_m + nbl_m, 256, 0, stream>>>(
        xgc, h_g, bp_g, g_ei, msg_g, EG, nbg_m,
        xlc, h_l, bp_l, lg_ei, msg_l, ELG);
    update_kernel<<<nbg_u + nbl_u, 256, 0, stream>>>(
        xgc, msg_g, cnt_g, el_g, rp_g, g_bias, xgn, NG, nbg_u,
        xlc, msg_l, cnt_l, el_l, rp_l, lg_bias, xln, NLG);
    u16* tmp = xgc; xgc = xgn; xgn = tmp;
    tmp = xlc; xlc = xln; xln = tmp;
  }

  // ---- pool + head: one dispatch (512 pool blocks + 24 head blocks, spin barriers) ----
  pool_head_kernel<<<536, 256, 0, stream>>>(
      xgc, pool_g, NG * 8, xlc, pool_l, NLG * 8,
      adduct, bott_w, bott_b, lin1_w, lin1_b, lin2_w, lin2_b,
      h0, h1, sctr, (float*)d_out);
}

// Round 17
// 436.512 us; speedup vs baseline: 1.4354x; 1.0160x over previous
//
#include <hip/hip_runtime.h>

typedef unsigned short u16;
using short8_t  = __attribute__((ext_vector_type(8)))  short;
using float16_t = __attribute__((ext_vector_type(16))) float;
using float2v   = __attribute__((ext_vector_type(2)))  float;

#define NKT 260          // K-steps of 16: K = 64*64 + 64 = 4160
#define DEG_CAP 32

__device__ __forceinline__ float bf2f(u16 b) { return __uint_as_float(((unsigned)b) << 16); }
__device__ __forceinline__ u16 f2bf(float f) {
  unsigned u = __float_as_uint(f);
  return (u16)((u + 0x7fffu + ((u >> 16) & 1u)) >> 16);   // RNE
}

union U8 { short8_t s; uint4 v; unsigned u[4]; };

// z = (h * x) truncated to bf16, unpack fused. Bit-identical to prior rounds.
__device__ __forceinline__ short8_t scale8r(U8 xr, float2v h2) {
  U8 out;
  #pragma unroll
  for (int p = 0; p < 4; ++p) {
    float2v r;
    r[0] = __uint_as_float(xr.u[p] << 16);
    r[1] = __uint_as_float(xr.u[p] & 0xffff0000u);
    r = r * h2;
    out.u[p] = __builtin_amdgcn_perm(__float_as_uint(r[1]), __float_as_uint(r[0]), 0x07060302);
  }
  return out.s;
}

// ---------------- mega-setup: affine x4 + pack x4 + all zero-fills, ONE dispatch ----------------
template<int IN>
__device__ __forceinline__ void affine_body(
    const float* __restrict__ Xin, const float* __restrict__ W, const float* __restrict__ Bv,
    u16* __restrict__ Xout, int N, int gid)
{
  int n = gid >> 6, o = gid & 63;
  if (n >= N) return;
  float acc = Bv[o];
  #pragma unroll
  for (int i = 0; i < IN; ++i)
    acc = fmaf(Xin[n * IN + i], W[i * 64 + o], acc);
  Xout[gid] = f2bf(fmaxf(acc, 0.f));
}

__device__ __forceinline__ void bpack_body(
    const float* __restrict__ w2, const float* __restrict__ b2, u16* __restrict__ Bp, int gid)
{
  if (gid >= NKT * 128) return;
  int lane = gid & 63;
  int nt = (gid >> 6) & 1;
  int kt = gid >> 7;
  int o = nt * 32 + (lane & 31);
  int kbase = kt * 16 + (lane >> 5) * 8;
  u16 vals[8];
  #pragma unroll
  for (int j = 0; j < 8; ++j) {
    int k = kbase + j;
    vals[j] = f2bf((k < 4096) ? w2[(k >> 6) * 4096 + (k & 63) * 64 + o]
                              : b2[(k - 4096) * 64 + o]);
  }
  uint4 pack;
  pack.x = (unsigned)vals[0] | ((unsigned)vals[1] << 16);
  pack.y = (unsigned)vals[2] | ((unsigned)vals[3] << 16);
  pack.z = (unsigned)vals[4] | ((unsigned)vals[5] << 16);
  pack.w = (unsigned)vals[6] | ((unsigned)vals[7] << 16);
  *(uint4*)(Bp + (size_t)gid * 8) = pack;
}

__device__ __forceinline__ void rootpack_body(const float* __restrict__ root, u16* __restrict__ Rp, int gid)
{
  if (gid >= 512) return;
  int lane = gid & 63;
  int nt = (gid >> 6) & 1;
  int kt = gid >> 7;
  int o = nt * 32 + (lane & 31);
  int kbase = kt * 16 + (lane >> 5) * 8;
  u16 vals[8];
  #pragma unroll
  for (int j = 0; j < 8; ++j) vals[j] = f2bf(root[(kbase + j) * 64 + o]);
  uint4 pack;
  pack.x = (unsigned)vals[0] | ((unsigned)vals[1] << 16);
  pack.y = (unsigned)vals[2] | ((unsigned)vals[3] << 16);
  pack.z = (unsigned)vals[4] | ((unsigned)vals[5] << 16);
  pack.w = (unsigned)vals[6] | ((unsigned)vals[7] << 16);
  *(uint4*)(Rp + (size_t)gid * 8) = pack;
}

__global__ __launch_bounds__(256) void setup_all_kernel(
    const float* __restrict__ gx, const float* __restrict__ l0w, const float* __restrict__ l0b, u16* __restrict__ xg,
    const float* __restrict__ lgx, const float* __restrict__ llw, const float* __restrict__ llb, u16* __restrict__ xl,
    const float* __restrict__ gea, const float* __restrict__ gw1, const float* __restrict__ gb1, u16* __restrict__ hg,
    const float* __restrict__ lea, const float* __restrict__ lw1, const float* __restrict__ lb1, u16* __restrict__ hl,
    const float* __restrict__ gw2, const float* __restrict__ gb2, u16* __restrict__ bpg,
    const float* __restrict__ lw2, const float* __restrict__ lb2, u16* __restrict__ bpl,
    const float* __restrict__ groot, u16* __restrict__ rpg,
    const float* __restrict__ lroot, u16* __restrict__ rpl,
    int B0, int B1, int B2, int B3, int B4, int B5, int B6, int B7, int B8,
    int NG, int NLG, int EG, int ELG,
    int* __restrict__ zero_ptr, int NZ, float* __restrict__ poolz, int* __restrict__ sync_ctr)
{
  int b = blockIdx.x, t = threadIdx.x;
  if (b < B0)       affine_body<20>(gx, l0w, l0b, xg, NG, b * 256 + t);
  else if (b < B1)  affine_body<5>(lgx, llw, llb, xl, NLG, (b - B0) * 256 + t);
  else if (b < B2)  affine_body<4>(gea, gw1, gb1, hg, EG, (b - B1) * 256 + t);
  else if (b < B3)  affine_body<1>(lea, lw1, lb1, hl, ELG, (b - B2) * 256 + t);
  else if (b < B4) {                       // cnt zero-fill
    int idx = (b - B3) * 256 + t;
    if (idx < NZ) zero_ptr[idx] = 0;
  }
  else if (b < B5)  bpack_body(gw2, gb2, bpg, (b - B4) * 256 + t);
  else if (b < B6)  bpack_body(lw2, lb2, bpl, (b - B5) * 256 + t);
  else if (b < B7)  rootpack_body(groot, rpg, (b - B6) * 256 + t);
  else if (b < B8)  rootpack_body(lroot, rpl, (b - B7) * 256 + t);
  else {                                   // pool buffers + sync counters
    if (t < 128) poolz[t] = 0.f;
    else if (t < 136) sync_ctr[t - 128] = 0;
  }
}

// ---------------- fused bucketed CSR ----------------
__device__ __forceinline__ void hist_body(
    const int* __restrict__ eidx, int* __restrict__ cnt, int* __restrict__ elist, int E, int e)
{
  if (e < E) {
    int tg = eidx[E + e];
    int pos = atomicAdd(cnt + tg, 1);
    if (pos < DEG_CAP) elist[(size_t)tg * DEG_CAP + pos] = e;
  }
}

__global__ __launch_bounds__(256) void hist_kernel(
    const int* __restrict__ eig, int* __restrict__ cg, int* __restrict__ elg, int Eg, int nbg,
    const int* __restrict__ eil, int* __restrict__ cl, int* __restrict__ ell, int El)
{
  int b = blockIdx.x, t = threadIdx.x;
  if (b < nbg) hist_body(eig, cg, elg, Eg, b * 256 + t);
  else         hist_body(eil, cl, ell, El, (b - nbg) * 256 + t);
}

// ---------------- msg = [h (x) x, x] @ B_ext — LDS ring, M=64/wave, 16KB chunks ----------------
// R8 config (best measured: 66us, MfmaUtil 40%). Untouched.
__global__ __launch_bounds__(256, 2) void msg_gemm_kernel(
    const u16* __restrict__ Xg, const u16* __restrict__ Hg, const u16* __restrict__ Bg,
    const int* __restrict__ eig, u16* __restrict__ Mg, int Eg, int nbg,
    const u16* __restrict__ Xl, const u16* __restrict__ Hl, const u16* __restrict__ Bl,
    const int* __restrict__ eil, u16* __restrict__ Ml, int El)
{
  __shared__ __align__(16) u16 sB[4][8192];   // 4 bufs x 16 KB ring

  const int b = blockIdx.x;
  const u16 *X, *Hh, *Bp; const int* eidx; u16* msg; int E, e0;
  if (b < nbg) { X = Xg; Hh = Hg; Bp = Bg; eidx = eig; msg = Mg; E = Eg; e0 = b * 256; }
  else         { X = Xl; Hh = Hl; Bp = Bl; eidx = eil; msg = Ml; E = El; e0 = (b - nbg) * 256; }

  const int t = threadIdx.x;
  const int lane = t & 63;
  const int wid = t >> 6;           // 4 waves x 64 edges = 256 edges/block
  const int ml = lane & 31;
  const int q  = lane >> 5;

  // stage chunks 0..2 immediately (12 DMAs) — overlap the x/h prologue gathers
  #pragma unroll
  for (int c0 = 0; c0 < 3; ++c0) {
    const u16* src = Bp + (size_t)c0 * 8192 + (size_t)wid * 2048 + (size_t)lane * 8;
    u16* dst = &sB[c0][wid * 2048];
    #pragma unroll
    for (int d = 0; d < 4; ++d)
      __builtin_amdgcn_global_load_lds((const __attribute__((address_space(1))) void*)(src + d * 512),
                                       (__attribute__((address_space(3))) void*)(dst + d * 512), 16, 0, 0);
  }

  const int ea  = e0 + wid * 64 + ml;       // tile0 row
  const int eb  = ea + 32;                  // tile1 row
  const int eac = ea < E ? ea : E - 1;
  const int ebc = eb < E ? eb : E - 1;
  const int sa  = eidx[eac], sb = eidx[ebc];

  // x raw bf16 (unpack fused into scale8r): 16 VGPR per tile
  U8 xra[4], xrb[4];
  {
    const u16* xpa = X + (size_t)sa * 64 + q * 8;
    const u16* xpb = X + (size_t)sb * 64 + q * 8;
    #pragma unroll
    for (int s = 0; s < 4; ++s) {
      xra[s].v = *(const uint4*)(xpa + s * 16);
      xrb[s].v = *(const uint4*)(xpb + s * 16);
    }
  }

  // h row streams (both tiles): one uint4 (8 h elems) per group of 4 chunks
  const uint4* ha4 = (const uint4*)(Hh + (size_t)eac * 64);
  const uint4* hb4 = (const uint4*)(Hh + (size_t)ebc * 64);
  uint4 hc0 = ha4[0], hn0 = ha4[1];
  uint4 hc1 = hb4[0], hn1 = hb4[1];

  float16_t acc00, acc01, acc10, acc11;
  #pragma unroll
  for (int i = 0; i < 16; ++i) { acc00[i] = 0.f; acc01[i] = 0.f; acc10[i] = 0.f; acc11[i] = 0.f; }

  // running DMA source pointer (chunk 3 first); bumped +8192 u16 per chunk
  const u16* bsrc = Bp + (size_t)3 * 8192 + (size_t)wid * 2048 + (size_t)lane * 8;

  const short8_t* sb8 = (const short8_t*)&sB[0][0];   // 16B-element view of the ring

  // prologue handoff: drain everything once, then one barrier. Loop never drains again.
  asm volatile("s_waitcnt vmcnt(0)" ::: "memory");
  __builtin_amdgcn_sched_barrier(0);
  __builtin_amdgcn_s_barrier();

  for (int g = 0; g < 8; ++g) {     // group = 4 chunks = 32 kt; hcur word cc -> 2 h-scalars
    #pragma unroll
    for (int cc = 0; cc < 4; ++cc) {
      {   // issue stage(c+3) into ring slot (cc+3)&3 — garbage chunks 33/34 land in Bp slack
        #pragma unroll
        for (int d = 0; d < 4; ++d)
          __builtin_amdgcn_global_load_lds((const __attribute__((address_space(1))) void*)(bsrc + d * 512),
                                           (__attribute__((address_space(3))) void*)(&sB[(cc + 3) & 3][wid * 2048] + d * 512), 16, 0, 0);
        bsrc += 8192;
      }
      unsigned w0 = ((const unsigned*)&hc0)[cc];                 // static index
      unsigned w1 = ((const unsigned*)&hc1)[cc];
      const int sbase = (cc & 3) * 1024;               // short8 index of ring slot (16KB = 1024 short8)
      #pragma unroll
      for (int hh = 0; hh < 2; ++hh) {                 // h-scalar within word: lo then hi
        float2v h20, h21;
        h20[0] = h20[1] = bf2f((u16)(hh ? (w0 >> 16) : (w0 & 0xffffu)));
        h21[0] = h21[1] = bf2f((u16)(hh ? (w1 >> 16) : (w1 & 0xffffu)));
        #pragma unroll
        for (int tt = 0; tt < 4; ++tt) {               // kt = 8c + 4hh + tt
          short8_t b0 = sb8[sbase + (hh * 4 + tt) * 128 + lane];
          short8_t b1 = sb8[sbase + (hh * 4 + tt) * 128 + 64 + lane];
          short8_t a0 = scale8r(xra[tt], h20);
          short8_t a1 = scale8r(xrb[tt], h21);
          acc00 = __builtin_amdgcn_mfma_f32_32x32x16_bf16(a0, b0, acc00, 0, 0, 0);
          acc01 = __builtin_amdgcn_mfma_f32_32x32x16_bf16(a0, b1, acc01, 0, 0, 0);
          acc10 = __builtin_amdgcn_mfma_f32_32x32x16_bf16(a1, b0, acc10, 0, 0, 0);
          acc11 = __builtin_amdgcn_mfma_f32_32x32x16_bf16(a1, b1, acc11, 0, 0, 0);
        }
      }
      // counted handoff: my ds_reads done (free), my stage(c+1) retired; c+2/c+3 in flight
      asm volatile("s_waitcnt lgkmcnt(0)" ::: "memory");
      asm volatile("s_waitcnt vmcnt(8)" ::: "memory");
      __builtin_amdgcn_sched_barrier(0);
      __builtin_amdgcn_s_barrier();
    }
    hc0 = hn0; hc1 = hn1;
    if (g < 6) { hn0 = ha4[g + 2]; hn1 = hb4[g + 2]; }
  }

  // tail: chunk 32 = kt 256..259 (b2 bias rows), A = x exactly (hs=1.0), ring slot 0
  {
    float2v h2; h2[0] = 1.0f; h2[1] = 1.0f;
    #pragma unroll
    for (int tt = 0; tt < 4; ++tt) {
      short8_t b0 = sb8[tt * 128 + lane];
      short8_t b1 = sb8[tt * 128 + 64 + lane];
      short8_t a0 = scale8r(xra[tt], h2);
      short8_t a1 = scale8r(xrb[tt], h2);
      acc00 = __builtin_amdgcn_mfma_f32_32x32x16_bf16(a0, b0, acc00, 0, 0, 0);
      acc01 = __builtin_amdgcn_mfma_f32_32x32x16_bf16(a0, b1, acc01, 0, 0, 0);
      acc10 = __builtin_amdgcn_mfma_f32_32x32x16_bf16(a1, b0, acc10, 0, 0, 0);
      acc11 = __builtin_amdgcn_mfma_f32_32x32x16_bf16(a1, b1, acc11, 0, 0, 0);
    }
  }

  // epilogue: C/D layout col=lane&31, row=(reg&3)+8*(reg>>2)+4*q; bf16 stores, both tiles
  #pragma unroll
  for (int reg = 0; reg < 16; ++reg) {
    int row = (reg & 3) + 8 * (reg >> 2) + 4 * q;
    int e1 = e0 + wid * 64 + row;
    int e2 = e1 + 32;
    if (e1 < E) {
      msg[(size_t)e1 * 64 + ml]      = f2bf(acc00[reg]);
      msg[(size_t)e1 * 64 + 32 + ml] = f2bf(acc01[reg]);
    }
    if (e2 < E) {
      msg[(size_t)e2 * 64 + ml]      = f2bf(acc10[reg]);
      msg[(size_t)e2 * 64 + 32 + ml] = f2bf(acc11[reg]);
    }
  }
}

// ---------------- x_new = relu(x @ root + gather_mean(msg) + bias) — MFMA, fused ----------------
// R17: software-pipelined gather. R16's groups ran A0 B0 A1 B1 ... — group g+1's
// independent loads stalled behind group g's branchy residual. New order:
// G0 G1 F0 G2 F1 G3 F2 F3 — each FINISH runs with the next GATHER's ~36 loads in
// flight. Literal-group macros keep all acc0[reg] indices compile-time (rule #20).
// Full cnt cached in gather (cf_) — removes redundant cnt reloads in FINISH.
// Arithmetic identical to R16 (absmax 0.0 verified). Live regs ~90 < 128 cap.
__global__ __launch_bounds__(256, 4) void update_kernel(
    const u16* __restrict__ Xig, const u16* __restrict__ Mgg, const int* __restrict__ cg,
    const int* __restrict__ elg, const u16* __restrict__ rpg, const float* __restrict__ bg,
    u16* __restrict__ Xog, int Ng, int nbg,
    const u16* __restrict__ Xil, const u16* __restrict__ Mgl, const int* __restrict__ cl,
    const int* __restrict__ ell, const u16* __restrict__ rpl, const float* __restrict__ bl,
    u16* __restrict__ Xol, int Nl)
{
  const int b = blockIdx.x;
  const u16 *Xin, *rootp, *msg; const float *bias; const int *cnt, *elist;
  u16* Xout; int N, n0;
  if (b < nbg) { Xin=Xig; msg=Mgg; cnt=cg; elist=elg; rootp=rpg; bias=bg; Xout=Xog; N=Ng; n0=b*128; }
  else         { Xin=Xil; msg=Mgl; cnt=cl; elist=ell; rootp=rpl; bias=bl; Xout=Xol; N=Nl; n0=(b-nbg)*128; }

  const int t = threadIdx.x;
  const int lane = t & 63;
  const int wid = t >> 6;
  const int ml = lane & 31;
  const int q  = lane >> 5;
  const int nbase = n0 + wid * 32;

  const int na = nbase + ml;
  const int nac = na < N ? na : N - 1;

  U8 xr[4];
  {
    const u16* xp = Xin + (size_t)nac * 64 + q * 8;
    #pragma unroll
    for (int s = 0; s < 4; ++s) xr[s].v = *(const uint4*)(xp + s * 16);
  }
  U8 rp[8];
  {
    const uint4* rpv = (const uint4*)rootp;
    #pragma unroll
    for (int i = 0; i < 8; ++i) rp[i].v = rpv[i * 64 + lane];
  }
  const float bias0 = bias[ml], bias1 = bias[32 + ml];

  float16_t acc0, acc1;
  #pragma unroll
  for (int i = 0; i < 16; ++i) { acc0[i] = 0.f; acc1[i] = 0.f; }
  #pragma unroll
  for (int kt = 0; kt < 4; ++kt) {
    acc0 = __builtin_amdgcn_mfma_f32_32x32x16_bf16(xr[kt].s, rp[kt * 2 + 0].s, acc0, 0, 0, 0);
    acc1 = __builtin_amdgcn_mfma_f32_32x32x16_bf16(xr[kt].s, rp[kt * 2 + 1].s, acc1, 0, 0, 0);
  }

  // GATHER(G): branch-free masked first-quad for 4 rows (literal G -> static reg idx)
  #define GATHER(G, nn_, cf_, cc_, a0_, a1_)                                               \
  {                                                                                        \
    _Pragma("unroll")                                                                      \
    for (int r = 0; r < 4; ++r) {                                                          \
      const int reg = (G) * 4 + r;                                                         \
      const int row = (reg & 3) + 8 * (reg >> 2) + 4 * q;                                  \
      const int nn = nbase + row;                                                          \
      nn_[r] = nn;                                                                         \
      const int nnc = nn < N ? nn : N - 1;                                                 \
      const int c = cnt[nnc];                                                              \
      cf_[r] = c;                                                                          \
      const int cc = c < DEG_CAP ? c : DEG_CAP;                                            \
      cc_[r] = cc;                                                                         \
      const int4 e4 = *(const int4*)(elist + (size_t)nnc * DEG_CAP);                       \
      int e0i = (cc > 0) ? e4.x : 0;                                                       \
      int e1i = (cc > 1) ? e4.y : 0;                                                       \
      int e2i = (cc > 2) ? e4.z : 0;                                                       \
      int e3i = (cc > 3) ? e4.w : 0;                                                       \
      float k0 = (cc > 0) ? 1.f : 0.f, k1 = (cc > 1) ? 1.f : 0.f;                          \
      float k2 = (cc > 2) ? 1.f : 0.f, k3 = (cc > 3) ? 1.f : 0.f;                          \
      float m00 = bf2f(msg[(size_t)e0i * 64 + ml]) * k0, m01 = bf2f(msg[(size_t)e0i * 64 + 32 + ml]) * k0; \
      float m10 = bf2f(msg[(size_t)e1i * 64 + ml]) * k1, m11 = bf2f(msg[(size_t)e1i * 64 + 32 + ml]) * k1; \
      float m20 = bf2f(msg[(size_t)e2i * 64 + ml]) * k2, m21 = bf2f(msg[(size_t)e2i * 64 + 32 + ml]) * k2; \
      float m30 = bf2f(msg[(size_t)e3i * 64 + ml]) * k3, m31 = bf2f(msg[(size_t)e3i * 64 + 32 + ml]) * k3; \
      a0_[r] = ((m00 + m10) + m20) + m30;                                                  \
      a1_[r] = ((m01 + m11) + m21) + m31;                                                  \
    }                                                                                      \
  }

  // FINISH(G): rare residual (cc > 4) — original quad+scalar tail from j=4 — then store
  #define FINISH(G, nn_, cf_, cc_, a0_, a1_)                                               \
  {                                                                                        \
    _Pragma("unroll")                                                                      \
    for (int r = 0; r < 4; ++r) {                                                          \
      const int reg = (G) * 4 + r;                                                         \
      const int nn = nn_[r];                                                               \
      if (nn < N) {                                                                        \
        const int c  = cf_[r];                                                             \
        const int cc = cc_[r];                                                             \
        float a0 = a0_[r], a1 = a1_[r];                                                    \
        if (cc > 4) {                                                                      \
          const int* ep = elist + (size_t)nn * DEG_CAP;                                    \
          int j = 4;                                                                       \
          for (; j + 4 <= cc; j += 4) {                                                    \
            int f0 = ep[j], f1 = ep[j + 1], f2 = ep[j + 2], f3 = ep[j + 3];                \
            u16 m00 = msg[(size_t)f0 * 64 + ml], m01 = msg[(size_t)f0 * 64 + 32 + ml];     \
            u16 m10 = msg[(size_t)f1 * 64 + ml], m11 = msg[(size_t)f1 * 64 + 32 + ml];     \
            u16 m20 = msg[(size_t)f2 * 64 + ml], m21 = msg[(size_t)f2 * 64 + 32 + ml];     \
            u16 m30 = msg[(size_t)f3 * 64 + ml], m31 = msg[(size_t)f3 * 64 + 32 + ml];     \
            a0 += bf2f(m00) + bf2f(m10) + bf2f(m20) + bf2f(m30);                           \
            a1 += bf2f(m01) + bf2f(m11) + bf2f(m21) + bf2f(m31);                           \
          }                                                                                \
          for (; j < cc; ++j) {                                                            \
            int e = ep[j];                                                                 \
            a0 += bf2f(msg[(size_t)e * 64 + ml]);                                          \
            a1 += bf2f(msg[(size_t)e * 64 + 32 + ml]);                                     \
          }                                                                                \
        }                                                                                  \
        float rc = (c > 1) ? (1.0f / (float)c) : 1.0f;                                     \
        float o0 = fmaxf(acc0[reg] + a0 * rc + bias0, 0.f);                                \
        float o1 = fmaxf(acc1[reg] + a1 * rc + bias1, 0.f);                                \
        Xout[(size_t)nn * 64 + ml]      = f2bf(o0);                                        \
        Xout[(size_t)nn * 64 + 32 + ml] = f2bf(o1);                                       \
      }                                                                                    \
    }                                                                                      \
  }

  // software pipeline: G0 G1 F0 G2 F1 G3 F2 F3 (two group-buffers A/B, all static)
  int nnA[4], cfA[4], ccA[4]; float a0A[4], a1A[4];
  int nnB[4], cfB[4], ccB[4]; float a0B[4], a1B[4];
  GATHER(0, nnA, cfA, ccA, a0A, a1A)
  GATHER(1, nnB, cfB, ccB, a0B, a1B)
  FINISH(0, nnA, cfA, ccA, a0A, a1A)
  GATHER(2, nnA, cfA, ccA, a0A, a1A)
  FINISH(1, nnB, cfB, ccB, a0B, a1B)
  GATHER(3, nnB, cfB, ccB, a0B, a1B)
  FINISH(2, nnA, cfA, ccA, a0A, a1A)
  FINISH(3, nnB, cfB, ccB, a0B, a1B)
  #undef GATHER
  #undef FINISH
}

// ---------------- pool + head in ONE dispatch (custom device-scope barriers) ----------------
__device__ __forceinline__ void pool_body(const u16* __restrict__ X, float* __restrict__ out64,
                                          int nchunks, int bid, int t)
{
  __shared__ float red[64];
  if (t < 64) red[t] = 0.f;
  __syncthreads();
  int gid = bid * 256 + t;
  float s[8];
  #pragma unroll
  for (int j = 0; j < 8; ++j) s[j] = 0.f;
  for (int i = gid; i < nchunks; i += 256 * 256) {
    uint4 v = ((const uint4*)X)[i];
    s[0] += bf2f((u16)(v.x & 0xffffu)); s[1] += bf2f((u16)(v.x >> 16));
    s[2] += bf2f((u16)(v.y & 0xffffu)); s[3] += bf2f((u16)(v.y >> 16));
    s[4] += bf2f((u16)(v.z & 0xffffu)); s[5] += bf2f((u16)(v.z >> 16));
    s[6] += bf2f((u16)(v.w & 0xffffu)); s[7] += bf2f((u16)(v.w >> 16));
  }
  int cg = (gid & 7) * 8;
  #pragma unroll
  for (int j = 0; j < 8; ++j) atomicAdd(red + cg + j, s[j]);
  __syncthreads();
  if (t < 64) atomicAdd(out64 + t, red[t]);
}

// block-level barrier among the 24 head blocks: monotonic counter, device-scope.
__device__ __forceinline__ void head_bar(int* ctr, int target, int t)
{
  __syncthreads();                         // all stores of this block issued
  if (t == 0) {
    __threadfence();                       // release: flush to coherent point
    atomicAdd(ctr, 1);
    while (atomicAdd(ctr, 0) < target)     // device-scope RMW read
      __builtin_amdgcn_s_sleep(2);
    __threadfence();                       // acquire: invalidate stale caches
  }
  __syncthreads();
}

__global__ __launch_bounds__(256) void pool_head_kernel(
    const u16* __restrict__ Xg, float* __restrict__ og, int ncg,
    const u16* __restrict__ Xl, float* __restrict__ ol, int ncl,
    const float* __restrict__ adduct,
    const float* __restrict__ bw, const float* __restrict__ bb,
    const float* __restrict__ l1w, const float* __restrict__ l1b,
    const float* __restrict__ l2w, const float* __restrict__ l2b,
    float* __restrict__ h0, float* __restrict__ h1,
    int* __restrict__ sync_ctr, float* __restrict__ out)
{
  const int b = blockIdx.x, t = threadIdx.x;

  if (b < 512) {          // pool producers (bit-identical to R12 pool)
    if (b < 256) pool_body(Xg, og, ncg, b, t);
    else         pool_body(Xl, ol, ncl, b - 256, t);
    __syncthreads();
    if (t == 0) { __threadfence(); atomicAdd(&sync_ctr[0], 1); }
    return;
  }

  // head blocks hb = 0..23 — wait for all 512 pool blocks
  const int hb = b - 512;
  if (t == 0) {
    while (atomicAdd(&sync_ctr[0], 0) < 512) __builtin_amdgcn_s_sleep(8);
    __threadfence();
  }
  __syncthreads();

  __shared__ float red[16][17];
  __shared__ float wred[4];
  const int ol_ = t & 15, ig = t >> 4;
  const int o = hb * 16 + ol_;

  // bott: relu(bb + [pool_g|pool_l|adduct] @ bw)  (identical order to gemv_bott)
  {
    float s = 0.f;
    for (int i = ig; i < 131; i += 16) {
      float v = (i < 64) ? og[i] : (i < 128 ? ol[i - 64] : adduct[i - 128]);
      s = fmaf(v, bw[i * 384 + o], s);
    }
    red[ig][ol_] = s;
    __syncthreads();
    if (t < 16) {
      int oo = hb * 16 + t;
      float acc = bb[oo];
      #pragma unroll
      for (int g = 0; g < 16; ++g) acc += red[g][t];
      h0[oo] = fmaxf(acc, 0.f);
    }
  }
  head_bar(&sync_ctr[1], 24, t);

  // 6x lin1 (identical arithmetic to gemv_relu_kernel)
  float* ua = h0; float* ub = h1;
  for (int L = 0; L < 6; ++L) {
    float s = 0.f;
    for (int i = ig; i < 384; i += 16)
      s = fmaf(ua[i], l1w[i * 384 + o], s);
    red[ig][ol_] = s;
    __syncthreads();
    if (t < 16) {
      int oo = hb * 16 + t;
      float acc = l1b[oo];
      #pragma unroll
      for (int g = 0; g < 16; ++g) acc += red[g][t];
      ub[oo] = fmaxf(acc, 0.f);
    }
    head_bar(&sync_ctr[1], 24 * (L + 2), t);
    float* tmp = ua; ua = ub; ub = tmp;
  }

  // final: u @ l2w + l2b -> scalar (head block 0; 256 threads, validated in R13)
  if (hb == 0) {
    float p = ua[t] * l2w[t];
    if (t < 128) p += ua[t + 256] * l2w[t + 256];
    #pragma unroll
    for (int off = 32; off > 0; off >>= 1) p += __shfl_down(p, off);
    if ((t & 63) == 0) wred[t >> 6] = p;
    __syncthreads();
    if (t == 0) {
      float s = l2b[0];
      #pragma unroll
      for (int i = 0; i < 4; ++i) s += wred[i];
      out[0] = s;
    }
  }
}

extern "C" void kernel_launch(void* const* d_in, const int* in_sizes, int n_in,
                              void* d_out, int out_size, void* d_ws, size_t ws_size,
                              hipStream_t stream)
{
  const int NG = 30000, EG = 60000, NLG = 60000, ELG = 60000;

  const float* gx      = (const float*)d_in[0];
  const int*   g_ei    = (const int*)  d_in[1];
  const float* g_ea    = (const float*)d_in[2];
  const float* lgx     = (const float*)d_in[3];
  const int*   lg_ei   = (const int*)  d_in[4];
  const float* lg_ea   = (const float*)d_in[5];
  const float* adduct  = (const float*)d_in[6];
  const float* lin0_w  = (const float*)d_in[7];
  const float* lin0_b  = (const float*)d_in[8];
  const float* g_w1    = (const float*)d_in[9];
  const float* g_b1    = (const float*)d_in[10];
  const float* g_w2    = (const float*)d_in[11];
  const float* g_b2    = (const float*)d_in[12];
  const float* g_root  = (const float*)d_in[13];
  const float* g_bias  = (const float*)d_in[14];
  const float* l0lg_w  = (const float*)d_in[15];
  const float* l0lg_b  = (const float*)d_in[16];
  const float* lg_w1   = (const float*)d_in[17];
  const float* lg_b1   = (const float*)d_in[18];
  const float* lg_w2   = (const float*)d_in[19];
  const float* lg_b2   = (const float*)d_in[20];
  const float* lg_root = (const float*)d_in[21];
  const float* lg_bias = (const float*)d_in[22];
  const float* bott_w  = (const float*)d_in[23];
  const float* bott_b  = (const float*)d_in[24];
  const float* lin1_w  = (const float*)d_in[25];
  const float* lin1_b  = (const float*)d_in[26];
  const float* lin2_w  = (const float*)d_in[27];
  const float* lin2_b  = (const float*)d_in[28];

  char* p = (char*)d_ws;
  auto alloc = [&](size_t bytes) { char* r = p; p += (bytes + 255) & ~(size_t)255; return r; };
  u16*   xg_a   = (u16*)  alloc((size_t)NG  * 64 * 2);
  u16*   xg_b   = (u16*)  alloc((size_t)NG  * 64 * 2);
  u16*   xl_a   = (u16*)  alloc((size_t)NLG * 64 * 2);
  u16*   xl_b   = (u16*)  alloc((size_t)NLG * 64 * 2);
  u16*   h_g    = (u16*)  alloc((size_t)EG  * 64 * 2);
  u16*   h_l    = (u16*)  alloc((size_t)ELG * 64 * 2);
  u16*   bp_g   = (u16*)  alloc((size_t)NKT * 128 * 8 * 2 + 49152);  // slack: 16KB chunks stage up to chunk 34
  u16*   bp_l   = (u16*)  alloc((size_t)NKT * 128 * 8 * 2 + 49152);
  u16*   rp_g   = (u16*)  alloc(512 * 8 * 2);
  u16*   rp_l   = (u16*)  alloc(512 * 8 * 2);
  u16*   msg_g  = (u16*)  alloc((size_t)EG  * 64 * 2);   // bf16 msg
  u16*   msg_l  = (u16*)  alloc((size_t)ELG * 64 * 2);
  int*   cnt_g  = (int*)  alloc((size_t)NG  * 4);   // cnt_g/cnt_l adjacent: single zero-fill span
  int*   cnt_l  = (int*)  alloc((size_t)NLG * 4);
  int*   el_g   = (int*)  alloc((size_t)NG  * DEG_CAP * 4);
  int*   el_l   = (int*)  alloc((size_t)NLG * DEG_CAP * 4);
  float* pool_g = (float*)alloc(64 * 4);            // pools adjacent: zeroed in setup
  float* pool_l = (float*)alloc(64 * 4);
  float* h0     = (float*)alloc(384 * 4);
  float* h1     = (float*)alloc(384 * 4);
  int*   sctr   = (int*)  alloc(8 * 4);             // [0]=pool_done, [1]=layer barrier

  // ---- mega-setup: affine x4 + cnt zero + pack x4 + pool/sync zero (1 dispatch) ----
  const int B0 = NG * 64 / 256, B1 = B0 + NLG * 64 / 256, B2 = B1 + EG * 64 / 256;
  const int B3 = B2 + ELG * 64 / 256;
  const int NZ = (int)(((size_t)((char*)cnt_l - (char*)cnt_g)) / 4) + NLG;  // span incl. align pad
  const int B4 = B3 + (NZ + 255) / 256;
  const int B5 = B4 + 130, B6 = B5 + 130, B7 = B6 + 2, B8 = B7 + 2;
  setup_all_kernel<<<B8 + 1, 256, 0, stream>>>(
      gx, lin0_w, lin0_b, xg_a, lgx, l0lg_w, l0lg_b, xl_a,
      g_ea, g_w1, g_b1, h_g, lg_ea, lg_w1, lg_b1, h_l,
      g_w2, g_b2, bp_g, lg_w2, lg_b2, bp_l, g_root, rp_g, lg_root, rp_l,
      B0, B1, B2, B3, B4, B5, B6, B7, B8,
      NG, NLG, EG, ELG, cnt_g, NZ, pool_g, sctr);
  const int nhg = (EG + 255) / 256, nhl = (ELG + 255) / 256;
  hist_kernel<<<nhg + nhl, 256, 0, stream>>>(g_ei, cnt_g, el_g, EG, nhg, lg_ei, cnt_l, el_l, ELG);

  // ---- fused 3-iteration loop (256 edges/block, 4 waves x 64 edges, 16KB-chunk LDS ring) ----
  const int nbg_m = (EG + 255) / 256, nbl_m = (ELG + 255) / 256;
  const int nbg_u = (NG + 127) / 128, nbl_u = (NLG + 127) / 128;
  u16 *xgc = xg_a, *xgn = xg_b, *xlc = xl_a, *xln = xl_b;
  for (int it = 0; it < 3; ++it) {
    msg_gemm_kernel<<<nbg_m + nbl_m, 256, 0, stream>>>(
        xgc, h_g, bp_g, g_ei, msg_g, EG, nbg_m,
        xlc, h_l, bp_l, lg_ei, msg_l, ELG);
    update_kernel<<<nbg_u + nbl_u, 256, 0, stream>>>(
        xgc, msg_g, cnt_g, el_g, rp_g, g_bias, xgn, NG, nbg_u,
        xlc, msg_l, cnt_l, el_l, rp_l, lg_bias, xln, NLG);
    u16* tmp = xgc; xgc = xgn; xgn = tmp;
    tmp = xlc; xlc = xln; xln = tmp;
  }

  // ---- pool + head: one dispatch (512 pool blocks + 24 head blocks, spin barriers) ----
  pool_head_kernel<<<536, 256, 0, stream>>>(
      xgc, pool_g, NG * 8, xlc, pool_l, NLG * 8,
      adduct, bott_w, bott_b, lin1_w, lin1_b, lin2_w, lin2_b,
      h0, h1, sctr, (float*)d_out);
}

// Round 19
// 425.491 us; speedup vs baseline: 1.4726x; 1.0259x over previous
//
#include <hip/hip_runtime.h>

typedef unsigned short u16;
using short8_t  = __attribute__((ext_vector_type(8)))  short;
using float16_t = __attribute__((ext_vector_type(16))) float;
using float2v   = __attribute__((ext_vector_type(2)))  float;

#define NKT 260          // K-steps of 16: K = 64*64 + 64 = 4160
#define DEG_CAP 32

__device__ __forceinline__ float bf2f(u16 b) { return __uint_as_float(((unsigned)b) << 16); }
__device__ __forceinline__ u16 f2bf(float f) {
  unsigned u = __float_as_uint(f);
  return (u16)((u + 0x7fffu + ((u >> 16) & 1u)) >> 16);   // RNE
}

union U8 { short8_t s; uint4 v; unsigned u[4]; };

// z = (h * x) truncated to bf16, unpack fused. Bit-identical to prior rounds.
__device__ __forceinline__ short8_t scale8r(U8 xr, float2v h2) {
  U8 out;
  #pragma unroll
  for (int p = 0; p < 4; ++p) {
    float2v r;
    r[0] = __uint_as_float(xr.u[p] << 16);
    r[1] = __uint_as_float(xr.u[p] & 0xffff0000u);
    r = r * h2;
    out.u[p] = __builtin_amdgcn_perm(__float_as_uint(r[1]), __float_as_uint(r[0]), 0x07060302);
  }
  return out.s;
}

// ---------------- mega-setup: affine x4 + pack x4 + all zero-fills, ONE dispatch ----------------
template<int IN>
__device__ __forceinline__ void affine_body(
    const float* __restrict__ Xin, const float* __restrict__ W, const float* __restrict__ Bv,
    u16* __restrict__ Xout, int N, int gid)
{
  int n = gid >> 6, o = gid & 63;
  if (n >= N) return;
  float acc = Bv[o];
  #pragma unroll
  for (int i = 0; i < IN; ++i)
    acc = fmaf(Xin[n * IN + i], W[i * 64 + o], acc);
  Xout[gid] = f2bf(fmaxf(acc, 0.f));
}

__device__ __forceinline__ void bpack_body(
    const float* __restrict__ w2, const float* __restrict__ b2, u16* __restrict__ Bp, int gid)
{
  if (gid >= NKT * 128) return;
  int lane = gid & 63;
  int nt = (gid >> 6) & 1;
  int kt = gid >> 7;
  int o = nt * 32 + (lane & 31);
  int kbase = kt * 16 + (lane >> 5) * 8;
  u16 vals[8];
  #pragma unroll
  for (int j = 0; j < 8; ++j) {
    int k = kbase + j;
    vals[j] = f2bf((k < 4096) ? w2[(k >> 6) * 4096 + (k & 63) * 64 + o]
                              : b2[(k - 4096) * 64 + o]);
  }
  uint4 pack;
  pack.x = (unsigned)vals[0] | ((unsigned)vals[1] << 16);
  pack.y = (unsigned)vals[2] | ((unsigned)vals[3] << 16);
  pack.z = (unsigned)vals[4] | ((unsigned)vals[5] << 16);
  pack.w = (unsigned)vals[6] | ((unsigned)vals[7] << 16);
  *(uint4*)(Bp + (size_t)gid * 8) = pack;
}

__device__ __forceinline__ void rootpack_body(const float* __restrict__ root, u16* __restrict__ Rp, int gid)
{
  if (gid >= 512) return;
  int lane = gid & 63;
  int nt = (gid >> 6) & 1;
  int kt = gid >> 7;
  int o = nt * 32 + (lane & 31);
  int kbase = kt * 16 + (lane >> 5) * 8;
  u16 vals[8];
  #pragma unroll
  for (int j = 0; j < 8; ++j) vals[j] = f2bf(root[(kbase + j) * 64 + o]);
  uint4 pack;
  pack.x = (unsigned)vals[0] | ((unsigned)vals[1] << 16);
  pack.y = (unsigned)vals[2] | ((unsigned)vals[3] << 16);
  pack.z = (unsigned)vals[4] | ((unsigned)vals[5] << 16);
  pack.w = (unsigned)vals[6] | ((unsigned)vals[7] << 16);
  *(uint4*)(Rp + (size_t)gid * 8) = pack;
}

__global__ __launch_bounds__(256) void setup_all_kernel(
    const float* __restrict__ gx, const float* __restrict__ l0w, const float* __restrict__ l0b, u16* __restrict__ xg,
    const float* __restrict__ lgx, const float* __restrict__ llw, const float* __restrict__ llb, u16* __restrict__ xl,
    const float* __restrict__ gea, const float* __restrict__ gw1, const float* __restrict__ gb1, u16* __restrict__ hg,
    const float* __restrict__ lea, const float* __restrict__ lw1, const float* __restrict__ lb1, u16* __restrict__ hl,
    const float* __restrict__ gw2, const float* __restrict__ gb2, u16* __restrict__ bpg,
    const float* __restrict__ lw2, const float* __restrict__ lb2, u16* __restrict__ bpl,
    const float* __restrict__ groot, u16* __restrict__ rpg,
    const float* __restrict__ lroot, u16* __restrict__ rpl,
    int B0, int B1, int B2, int B3, int B4, int B5, int B6, int B7, int B8,
    int NG, int NLG, int EG, int ELG,
    int* __restrict__ zero_ptr, int NZ, float* __restrict__ poolz, int* __restrict__ sync_ctr)
{
  int b = blockIdx.x, t = threadIdx.x;
  if (b < B0)       affine_body<20>(gx, l0w, l0b, xg, NG, b * 256 + t);
  else if (b < B1)  affine_body<5>(lgx, llw, llb, xl, NLG, (b - B0) * 256 + t);
  else if (b < B2)  affine_body<4>(gea, gw1, gb1, hg, EG, (b - B1) * 256 + t);
  else if (b < B3)  affine_body<1>(lea, lw1, lb1, hl, ELG, (b - B2) * 256 + t);
  else if (b < B4) {                       // cnt zero-fill
    int idx = (b - B3) * 256 + t;
    if (idx < NZ) zero_ptr[idx] = 0;
  }
  else if (b < B5)  bpack_body(gw2, gb2, bpg, (b - B4) * 256 + t);
  else if (b < B6)  bpack_body(lw2, lb2, bpl, (b - B5) * 256 + t);
  else if (b < B7)  rootpack_body(groot, rpg, (b - B6) * 256 + t);
  else if (b < B8)  rootpack_body(lroot, rpl, (b - B7) * 256 + t);
  else {                                   // pool buffers + sync counters
    if (t < 128) poolz[t] = 0.f;
    else if (t < 136) sync_ctr[t - 128] = 0;
  }
}

// ---------------- fused bucketed CSR ----------------
__device__ __forceinline__ void hist_body(
    const int* __restrict__ eidx, int* __restrict__ cnt, int* __restrict__ elist, int E, int e)
{
  if (e < E) {
    int tg = eidx[E + e];
    int pos = atomicAdd(cnt + tg, 1);
    if (pos < DEG_CAP) elist[(size_t)tg * DEG_CAP + pos] = e;
  }
}

__global__ __launch_bounds__(256) void hist_kernel(
    const int* __restrict__ eig, int* __restrict__ cg, int* __restrict__ elg, int Eg, int nbg,
    const int* __restrict__ eil, int* __restrict__ cl, int* __restrict__ ell, int El)
{
  int b = blockIdx.x, t = threadIdx.x;
  if (b < nbg) hist_body(eig, cg, elg, Eg, b * 256 + t);
  else         hist_body(eil, cl, ell, El, (b - nbg) * 256 + t);
}

// ---------------- msg = [h (x) x, x] @ B_ext — LDS ring, M=64/wave, 16KB chunks ----------------
// R8 config (best measured: 66us, MfmaUtil 40%). Untouched.
__global__ __launch_bounds__(256, 2) void msg_gemm_kernel(
    const u16* __restrict__ Xg, const u16* __restrict__ Hg, const u16* __restrict__ Bg,
    const int* __restrict__ eig, u16* __restrict__ Mg, int Eg, int nbg,
    const u16* __restrict__ Xl, const u16* __restrict__ Hl, const u16* __restrict__ Bl,
    const int* __restrict__ eil, u16* __restrict__ Ml, int El)
{
  __shared__ __align__(16) u16 sB[4][8192];   // 4 bufs x 16 KB ring

  const int b = blockIdx.x;
  const u16 *X, *Hh, *Bp; const int* eidx; u16* msg; int E, e0;
  if (b < nbg) { X = Xg; Hh = Hg; Bp = Bg; eidx = eig; msg = Mg; E = Eg; e0 = b * 256; }
  else         { X = Xl; Hh = Hl; Bp = Bl; eidx = eil; msg = Ml; E = El; e0 = (b - nbg) * 256; }

  const int t = threadIdx.x;
  const int lane = t & 63;
  const int wid = t >> 6;           // 4 waves x 64 edges = 256 edges/block
  const int ml = lane & 31;
  const int q  = lane >> 5;

  // stage chunks 0..2 immediately (12 DMAs) — overlap the x/h prologue gathers
  #pragma unroll
  for (int c0 = 0; c0 < 3; ++c0) {
    const u16* src = Bp + (size_t)c0 * 8192 + (size_t)wid * 2048 + (size_t)lane * 8;
    u16* dst = &sB[c0][wid * 2048];
    #pragma unroll
    for (int d = 0; d < 4; ++d)
      __builtin_amdgcn_global_load_lds((const __attribute__((address_space(1))) void*)(src + d * 512),
                                       (__attribute__((address_space(3))) void*)(dst + d * 512), 16, 0, 0);
  }

  const int ea  = e0 + wid * 64 + ml;       // tile0 row
  const int eb  = ea + 32;                  // tile1 row
  const int eac = ea < E ? ea : E - 1;
  const int ebc = eb < E ? eb : E - 1;
  const int sa  = eidx[eac], sb = eidx[ebc];

  // x raw bf16 (unpack fused into scale8r): 16 VGPR per tile
  U8 xra[4], xrb[4];
  {
    const u16* xpa = X + (size_t)sa * 64 + q * 8;
    const u16* xpb = X + (size_t)sb * 64 + q * 8;
    #pragma unroll
    for (int s = 0; s < 4; ++s) {
      xra[s].v = *(const uint4*)(xpa + s * 16);
      xrb[s].v = *(const uint4*)(xpb + s * 16);
    }
  }

  // h row streams (both tiles): one uint4 (8 h elems) per group of 4 chunks
  const uint4* ha4 = (const uint4*)(Hh + (size_t)eac * 64);
  const uint4* hb4 = (const uint4*)(Hh + (size_t)ebc * 64);
  uint4 hc0 = ha4[0], hn0 = ha4[1];
  uint4 hc1 = hb4[0], hn1 = hb4[1];

  float16_t acc00, acc01, acc10, acc11;
  #pragma unroll
  for (int i = 0; i < 16; ++i) { acc00[i] = 0.f; acc01[i] = 0.f; acc10[i] = 0.f; acc11[i] = 0.f; }

  // running DMA source pointer (chunk 3 first); bumped +8192 u16 per chunk
  const u16* bsrc = Bp + (size_t)3 * 8192 + (size_t)wid * 2048 + (size_t)lane * 8;

  const short8_t* sb8 = (const short8_t*)&sB[0][0];   // 16B-element view of the ring

  // prologue handoff: drain everything once, then one barrier. Loop never drains again.
  asm volatile("s_waitcnt vmcnt(0)" ::: "memory");
  __builtin_amdgcn_sched_barrier(0);
  __builtin_amdgcn_s_barrier();

  for (int g = 0; g < 8; ++g) {     // group = 4 chunks = 32 kt; hcur word cc -> 2 h-scalars
    #pragma unroll
    for (int cc = 0; cc < 4; ++cc) {
      {   // issue stage(c+3) into ring slot (cc+3)&3 — garbage chunks 33/34 land in Bp slack
        #pragma unroll
        for (int d = 0; d < 4; ++d)
          __builtin_amdgcn_global_load_lds((const __attribute__((address_space(1))) void*)(bsrc + d * 512),
                                           (__attribute__((address_space(3))) void*)(&sB[(cc + 3) & 3][wid * 2048] + d * 512), 16, 0, 0);
        bsrc += 8192;
      }
      unsigned w0 = ((const unsigned*)&hc0)[cc];                 // static index
      unsigned w1 = ((const unsigned*)&hc1)[cc];
      const int sbase = (cc & 3) * 1024;               // short8 index of ring slot (16KB = 1024 short8)
      #pragma unroll
      for (int hh = 0; hh < 2; ++hh) {                 // h-scalar within word: lo then hi
        float2v h20, h21;
        h20[0] = h20[1] = bf2f((u16)(hh ? (w0 >> 16) : (w0 & 0xffffu)));
        h21[0] = h21[1] = bf2f((u16)(hh ? (w1 >> 16) : (w1 & 0xffffu)));
        #pragma unroll
        for (int tt = 0; tt < 4; ++tt) {               // kt = 8c + 4hh + tt
          short8_t b0 = sb8[sbase + (hh * 4 + tt) * 128 + lane];
          short8_t b1 = sb8[sbase + (hh * 4 + tt) * 128 + 64 + lane];
          short8_t a0 = scale8r(xra[tt], h20);
          short8_t a1 = scale8r(xrb[tt], h21);
          acc00 = __builtin_amdgcn_mfma_f32_32x32x16_bf16(a0, b0, acc00, 0, 0, 0);
          acc01 = __builtin_amdgcn_mfma_f32_32x32x16_bf16(a0, b1, acc01, 0, 0, 0);
          acc10 = __builtin_amdgcn_mfma_f32_32x32x16_bf16(a1, b0, acc10, 0, 0, 0);
          acc11 = __builtin_amdgcn_mfma_f32_32x32x16_bf16(a1, b1, acc11, 0, 0, 0);
        }
      }
      // counted handoff: my ds_reads done (free), my stage(c+1) retired; c+2/c+3 in flight
      asm volatile("s_waitcnt lgkmcnt(0)" ::: "memory");
      asm volatile("s_waitcnt vmcnt(8)" ::: "memory");
      __builtin_amdgcn_sched_barrier(0);
      __builtin_amdgcn_s_barrier();
    }
    hc0 = hn0; hc1 = hn1;
    if (g < 6) { hn0 = ha4[g + 2]; hn1 = hb4[g + 2]; }
  }

  // tail: chunk 32 = kt 256..259 (b2 bias rows), A = x exactly (hs=1.0), ring slot 0
  {
    float2v h2; h2[0] = 1.0f; h2[1] = 1.0f;
    #pragma unroll
    for (int tt = 0; tt < 4; ++tt) {
      short8_t b0 = sb8[tt * 128 + lane];
      short8_t b1 = sb8[tt * 128 + 64 + lane];
      short8_t a0 = scale8r(xra[tt], h2);
      short8_t a1 = scale8r(xrb[tt], h2);
      acc00 = __builtin_amdgcn_mfma_f32_32x32x16_bf16(a0, b0, acc00, 0, 0, 0);
      acc01 = __builtin_amdgcn_mfma_f32_32x32x16_bf16(a0, b1, acc01, 0, 0, 0);
      acc10 = __builtin_amdgcn_mfma_f32_32x32x16_bf16(a1, b0, acc10, 0, 0, 0);
      acc11 = __builtin_amdgcn_mfma_f32_32x32x16_bf16(a1, b1, acc11, 0, 0, 0);
    }
  }

  // epilogue: C/D layout col=lane&31, row=(reg&3)+8*(reg>>2)+4*q; bf16 stores, both tiles
  #pragma unroll
  for (int reg = 0; reg < 16; ++reg) {
    int row = (reg & 3) + 8 * (reg >> 2) + 4 * q;
    int e1 = e0 + wid * 64 + row;
    int e2 = e1 + 32;
    if (e1 < E) {
      msg[(size_t)e1 * 64 + ml]      = f2bf(acc00[reg]);
      msg[(size_t)e1 * 64 + 32 + ml] = f2bf(acc01[reg]);
    }
    if (e2 < E) {
      msg[(size_t)e2 * 64 + ml]      = f2bf(acc10[reg]);
      msg[(size_t)e2 * 64 + 32 + ml] = f2bf(acc11[reg]);
    }
  }
}

// ---------------- x_new = relu(x @ root + gather_mean(msg) + bias) — MFMA, fused ----------------
// R18: R17's pipelined gather + pool fused into the final iteration's epilogue.
// Each thread already holds its 16 relu outputs — accumulate bf2f(f2bf(o)) (the
// STORED value, matching what pool_body re-read) into per-thread partials, LDS
// 64-slot atomic reduce, one global atomicAdd per col per block. Pool kernel and
// its 11.5 MB read-back disappear. f32 atomic order was already nondeterministic
// in pool_body (absmax 0.0 for 17 rounds).
// (R18 bench was an infra failure — container acquisition; resubmitted unchanged.)
__global__ __launch_bounds__(256, 4) void update_kernel(
    const u16* __restrict__ Xig, const u16* __restrict__ Mgg, const int* __restrict__ cg,
    const int* __restrict__ elg, const u16* __restrict__ rpg, const float* __restrict__ bg,
    u16* __restrict__ Xog, int Ng, int nbg,
    const u16* __restrict__ Xil, const u16* __restrict__ Mgl, const int* __restrict__ cl,
    const int* __restrict__ ell, const u16* __restrict__ rpl, const float* __restrict__ bl,
    u16* __restrict__ Xol, int Nl,
    float* __restrict__ pg_pool, float* __restrict__ pl_pool, int do_pool)
{
  __shared__ float pred[64];

  const int b = blockIdx.x;
  const u16 *Xin, *rootp, *msg; const float *bias; const int *cnt, *elist;
  u16* Xout; float* poolbuf; int N, n0;
  if (b < nbg) { Xin=Xig; msg=Mgg; cnt=cg; elist=elg; rootp=rpg; bias=bg; Xout=Xog; poolbuf=pg_pool; N=Ng; n0=b*128; }
  else         { Xin=Xil; msg=Mgl; cnt=cl; elist=ell; rootp=rpl; bias=bl; Xout=Xol; poolbuf=pl_pool; N=Nl; n0=(b-nbg)*128; }

  const int t = threadIdx.x;
  const int lane = t & 63;
  const int wid = t >> 6;
  const int ml = lane & 31;
  const int q  = lane >> 5;
  const int nbase = n0 + wid * 32;

  const int na = nbase + ml;
  const int nac = na < N ? na : N - 1;

  U8 xr[4];
  {
    const u16* xp = Xin + (size_t)nac * 64 + q * 8;
    #pragma unroll
    for (int s = 0; s < 4; ++s) xr[s].v = *(const uint4*)(xp + s * 16);
  }
  U8 rp[8];
  {
    const uint4* rpv = (const uint4*)rootp;
    #pragma unroll
    for (int i = 0; i < 8; ++i) rp[i].v = rpv[i * 64 + lane];
  }
  const float bias0 = bias[ml], bias1 = bias[32 + ml];

  float16_t acc0, acc1;
  #pragma unroll
  for (int i = 0; i < 16; ++i) { acc0[i] = 0.f; acc1[i] = 0.f; }
  #pragma unroll
  for (int kt = 0; kt < 4; ++kt) {
    acc0 = __builtin_amdgcn_mfma_f32_32x32x16_bf16(xr[kt].s, rp[kt * 2 + 0].s, acc0, 0, 0, 0);
    acc1 = __builtin_amdgcn_mfma_f32_32x32x16_bf16(xr[kt].s, rp[kt * 2 + 1].s, acc1, 0, 0, 0);
  }

  float ps0 = 0.f, ps1 = 0.f;   // pool partials (cols ml / 32+ml)

  // GATHER(G): branch-free masked first-quad for 4 rows (literal G -> static reg idx)
  #define GATHER(G, nn_, cf_, cc_, a0_, a1_)                                               \
  {                                                                                        \
    _Pragma("unroll")                                                                      \
    for (int r = 0; r < 4; ++r) {                                                          \
      const int reg = (G) * 4 + r;                                                         \
      const int row = (reg & 3) + 8 * (reg >> 2) + 4 * q;                                  \
      const int nn = nbase + row;                                                          \
      nn_[r] = nn;                                                                         \
      const int nnc = nn < N ? nn : N - 1;                                                 \
      const int c = cnt[nnc];                                                              \
      cf_[r] = c;                                                                          \
      const int cc = c < DEG_CAP ? c : DEG_CAP;                                            \
      cc_[r] = cc;                                                                         \
      const int4 e4 = *(const int4*)(elist + (size_t)nnc * DEG_CAP);                       \
      int e0i = (cc > 0) ? e4.x : 0;                                                       \
      int e1i = (cc > 1) ? e4.y : 0;                                                       \
      int e2i = (cc > 2) ? e4.z : 0;                                                       \
      int e3i = (cc > 3) ? e4.w : 0;                                                       \
      float k0 = (cc > 0) ? 1.f : 0.f, k1 = (cc > 1) ? 1.f : 0.f;                          \
      float k2 = (cc > 2) ? 1.f : 0.f, k3 = (cc > 3) ? 1.f : 0.f;                          \
      float m00 = bf2f(msg[(size_t)e0i * 64 + ml]) * k0, m01 = bf2f(msg[(size_t)e0i * 64 + 32 + ml]) * k0; \
      float m10 = bf2f(msg[(size_t)e1i * 64 + ml]) * k1, m11 = bf2f(msg[(size_t)e1i * 64 + 32 + ml]) * k1; \
      float m20 = bf2f(msg[(size_t)e2i * 64 + ml]) * k2, m21 = bf2f(msg[(size_t)e2i * 64 + 32 + ml]) * k2; \
      float m30 = bf2f(msg[(size_t)e3i * 64 + ml]) * k3, m31 = bf2f(msg[(size_t)e3i * 64 + 32 + ml]) * k3; \
      a0_[r] = ((m00 + m10) + m20) + m30;                                                  \
      a1_[r] = ((m01 + m11) + m21) + m31;                                                  \
    }                                                                                      \
  }

  // FINISH(G): rare residual (cc > 4) — original quad+scalar tail from j=4 — store + pool
  #define FINISH(G, nn_, cf_, cc_, a0_, a1_)                                               \
  {                                                                                        \
    _Pragma("unroll")                                                                      \
    for (int r = 0; r < 4; ++r) {                                                          \
      const int reg = (G) * 4 + r;                                                         \
      const int nn = nn_[r];                                                               \
      if (nn < N) {                                                                        \
        const int c  = cf_[r];                                                             \
        const int cc = cc_[r];                                                             \
        float a0 = a0_[r], a1 = a1_[r];                                                    \
        if (cc > 4) {                                                                      \
          const int* ep = elist + (size_t)nn * DEG_CAP;                                    \
          int j = 4;                                                                       \
          for (; j + 4 <= cc; j += 4) {                                                    \
            int f0 = ep[j], f1 = ep[j + 1], f2 = ep[j + 2], f3 = ep[j + 3];                \
            u16 m00 = msg[(size_t)f0 * 64 + ml], m01 = msg[(size_t)f0 * 64 + 32 + ml];     \
            u16 m10 = msg[(size_t)f1 * 64 + ml], m11 = msg[(size_t)f1 * 64 + 32 + ml];     \
            u16 m20 = msg[(size_t)f2 * 64 + ml], m21 = msg[(size_t)f2 * 64 + 32 + ml];     \
            u16 m30 = msg[(size_t)f3 * 64 + ml], m31 = msg[(size_t)f3 * 64 + 32 + ml];     \
            a0 += bf2f(m00) + bf2f(m10) + bf2f(m20) + bf2f(m30);                           \
            a1 += bf2f(m01) + bf2f(m11) + bf2f(m21) + bf2f(m31);                           \
          }                                                                                \
          for (; j < cc; ++j) {                                                            \
            int e = ep[j];                                                                 \
            a0 += bf2f(msg[(size_t)e * 64 + ml]);                                          \
            a1 += bf2f(msg[(size_t)e * 64 + 32 + ml]);                                     \
          }                                                                                \
        }                                                                                  \
        float rc = (c > 1) ? (1.0f / (float)c) : 1.0f;                                     \
        float o0 = fmaxf(acc0[reg] + a0 * rc + bias0, 0.f);                                \
        float o1 = fmaxf(acc1[reg] + a1 * rc + bias1, 0.f);                                \
        u16 s0 = f2bf(o0), s1 = f2bf(o1);                                                  \
        Xout[(size_t)nn * 64 + ml]      = s0;                                              \
        Xout[(size_t)nn * 64 + 32 + ml] = s1;                                              \
        ps0 += bf2f(s0);                                                                   \
        ps1 += bf2f(s1);                                                                   \
      }                                                                                    \
    }                                                                                      \
  }

  // software pipeline: G0 G1 F0 G2 F1 G3 F2 F3 (two group-buffers A/B, all static)
  int nnA[4], cfA[4], ccA[4]; float a0A[4], a1A[4];
  int nnB[4], cfB[4], ccB[4]; float a0B[4], a1B[4];
  GATHER(0, nnA, cfA, ccA, a0A, a1A)
  GATHER(1, nnB, cfB, ccB, a0B, a1B)
  FINISH(0, nnA, cfA, ccA, a0A, a1A)
  GATHER(2, nnA, cfA, ccA, a0A, a1A)
  FINISH(1, nnB, cfB, ccB, a0B, a1B)
  GATHER(3, nnB, cfB, ccB, a0B, a1B)
  FINISH(2, nnA, cfA, ccA, a0A, a1A)
  FINISH(3, nnB, cfB, ccB, a0B, a1B)
  #undef GATHER
  #undef FINISH

  // fused pool epilogue (final iteration only)
  if (do_pool) {
    if (t < 64) pred[t] = 0.f;
    __syncthreads();
    atomicAdd(&pred[ml], ps0);
    atomicAdd(&pred[32 + ml], ps1);
    __syncthreads();
    if (t < 64) atomicAdd(poolbuf + t, pred[t]);
  }
}

// block-level barrier among the 24 head blocks: monotonic counter, device-scope.
__device__ __forceinline__ void head_bar(int* ctr, int target, int t)
{
  __syncthreads();                         // all stores of this block issued
  if (t == 0) {
    __threadfence();                       // release: flush to coherent point
    atomicAdd(ctr, 1);
    while (atomicAdd(ctr, 0) < target)     // device-scope RMW read
      __builtin_amdgcn_s_sleep(2);
    __threadfence();                       // acquire: invalidate stale caches
  }
  __syncthreads();
}

// ---------------- head-only: bott + 6x lin1 + final (24 blocks, spin barriers) ----------------
// Pool results are ready by stream order (update it=2 fused them) — no pool wait.
__global__ __launch_bounds__(256) void head_kernel(
    const float* __restrict__ og, const float* __restrict__ ol,
    const float* __restrict__ adduct,
    const float* __restrict__ bw, const float* __restrict__ bb,
    const float* __restrict__ l1w, const float* __restrict__ l1b,
    const float* __restrict__ l2w, const float* __restrict__ l2b,
    float* __restrict__ h0, float* __restrict__ h1,
    int* __restrict__ sync_ctr, float* __restrict__ out)
{
  const int hb = blockIdx.x, t = threadIdx.x;

  __shared__ float red[16][17];
  __shared__ float wred[4];
  const int ol_ = t & 15, ig = t >> 4;
  const int o = hb * 16 + ol_;

  // bott: relu(bb + [pool_g|pool_l|adduct] @ bw)  (identical order to gemv_bott)
  {
    float s = 0.f;
    for (int i = ig; i < 131; i += 16) {
      float v = (i < 64) ? og[i] : (i < 128 ? ol[i - 64] : adduct[i - 128]);
      s = fmaf(v, bw[i * 384 + o], s);
    }
    red[ig][ol_] = s;
    __syncthreads();
    if (t < 16) {
      int oo = hb * 16 + t;
      float acc = bb[oo];
      #pragma unroll
      for (int g = 0; g < 16; ++g) acc += red[g][t];
      h0[oo] = fmaxf(acc, 0.f);
    }
  }
  head_bar(&sync_ctr[1], 24, t);

  // 6x lin1 (identical arithmetic to gemv_relu_kernel)
  float* ua = h0; float* ub = h1;
  for (int L = 0; L < 6; ++L) {
    float s = 0.f;
    for (int i = ig; i < 384; i += 16)
      s = fmaf(ua[i], l1w[i * 384 + o], s);
    red[ig][ol_] = s;
    __syncthreads();
    if (t < 16) {
      int oo = hb * 16 + t;
      float acc = l1b[oo];
      #pragma unroll
      for (int g = 0; g < 16; ++g) acc += red[g][t];
      ub[oo] = fmaxf(acc, 0.f);
    }
    head_bar(&sync_ctr[1], 24 * (L + 2), t);
    float* tmp = ua; ua = ub; ub = tmp;
  }

  // final: u @ l2w + l2b -> scalar (head block 0; 256 threads, validated in R13)
  if (hb == 0) {
    float p = ua[t] * l2w[t];
    if (t < 128) p += ua[t + 256] * l2w[t + 256];
    #pragma unroll
    for (int off = 32; off > 0; off >>= 1) p += __shfl_down(p, off);
    if ((t & 63) == 0) wred[t >> 6] = p;
    __syncthreads();
    if (t == 0) {
      float s = l2b[0];
      #pragma unroll
      for (int i = 0; i < 4; ++i) s += wred[i];
      out[0] = s;
    }
  }
}

extern "C" void kernel_launch(void* const* d_in, const int* in_sizes, int n_in,
                              void* d_out, int out_size, void* d_ws, size_t ws_size,
                              hipStream_t stream)
{
  const int NG = 30000, EG = 60000, NLG = 60000, ELG = 60000;

  const float* gx      = (const float*)d_in[0];
  const int*   g_ei    = (const int*)  d_in[1];
  const float* g_ea    = (const float*)d_in[2];
  const float* lgx     = (const float*)d_in[3];
  const int*   lg_ei   = (const int*)  d_in[4];
  const float* lg_ea   = (const float*)d_in[5];
  const float* adduct  = (const float*)d_in[6];
  const float* lin0_w  = (const float*)d_in[7];
  const float* lin0_b  = (const float*)d_in[8];
  const float* g_w1    = (const float*)d_in[9];
  const float* g_b1    = (const float*)d_in[10];
  const float* g_w2    = (const float*)d_in[11];
  const float* g_b2    = (const float*)d_in[12];
  const float* g_root  = (const float*)d_in[13];
  const float* g_bias  = (const float*)d_in[14];
  const float* l0lg_w  = (const float*)d_in[15];
  const float* l0lg_b  = (const float*)d_in[16];
  const float* lg_w1   = (const float*)d_in[17];
  const float* lg_b1   = (const float*)d_in[18];
  const float* lg_w2   = (const float*)d_in[19];
  const float* lg_b2   = (const float*)d_in[20];
  const float* lg_root = (const float*)d_in[21];
  const float* lg_bias = (const float*)d_in[22];
  const float* bott_w  = (const float*)d_in[23];
  const float* bott_b  = (const float*)d_in[24];
  const float* lin1_w  = (const float*)d_in[25];
  const float* lin1_b  = (const float*)d_in[26];
  const float* lin2_w  = (const float*)d_in[27];
  const float* lin2_b  = (const float*)d_in[28];

  char* p = (char*)d_ws;
  auto alloc = [&](size_t bytes) { char* r = p; p += (bytes + 255) & ~(size_t)255; return r; };
  u16*   xg_a   = (u16*)  alloc((size_t)NG  * 64 * 2);
  u16*   xg_b   = (u16*)  alloc((size_t)NG  * 64 * 2);
  u16*   xl_a   = (u16*)  alloc((size_t)NLG * 64 * 2);
  u16*   xl_b   = (u16*)  alloc((size_t)NLG * 64 * 2);
  u16*   h_g    = (u16*)  alloc((size_t)EG  * 64 * 2);
  u16*   h_l    = (u16*)  alloc((size_t)ELG * 64 * 2);
  u16*   bp_g   = (u16*)  alloc((size_t)NKT * 128 * 8 * 2 + 49152);  // slack: 16KB chunks stage up to chunk 34
  u16*   bp_l   = (u16*)  alloc((size_t)NKT * 128 * 8 * 2 + 49152);
  u16*   rp_g   = (u16*)  alloc(512 * 8 * 2);
  u16*   rp_l   = (u16*)  alloc(512 * 8 * 2);
  u16*   msg_g  = (u16*)  alloc((size_t)EG  * 64 * 2);   // bf16 msg
  u16*   msg_l  = (u16*)  alloc((size_t)ELG * 64 * 2);
  int*   cnt_g  = (int*)  alloc((size_t)NG  * 4);   // cnt_g/cnt_l adjacent: single zero-fill span
  int*   cnt_l  = (int*)  alloc((size_t)NLG * 4);
  int*   el_g   = (int*)  alloc((size_t)NG  * DEG_CAP * 4);
  int*   el_l   = (int*)  alloc((size_t)NLG * DEG_CAP * 4);
  float* pool_g = (float*)alloc(64 * 4);            // pools adjacent: zeroed in setup
  float* pool_l = (float*)alloc(64 * 4);
  float* h0     = (float*)alloc(384 * 4);
  float* h1     = (float*)alloc(384 * 4);
  int*   sctr   = (int*)  alloc(8 * 4);             // [1]=head layer barrier

  // ---- mega-setup: affine x4 + cnt zero + pack x4 + pool/sync zero (1 dispatch) ----
  const int B0 = NG * 64 / 256, B1 = B0 + NLG * 64 / 256, B2 = B1 + EG * 64 / 256;
  const int B3 = B2 + ELG * 64 / 256;
  const int NZ = (int)(((size_t)((char*)cnt_l - (char*)cnt_g)) / 4) + NLG;  // span incl. align pad
  const int B4 = B3 + (NZ + 255) / 256;
  const int B5 = B4 + 130, B6 = B5 + 130, B7 = B6 + 2, B8 = B7 + 2;
  setup_all_kernel<<<B8 + 1, 256, 0, stream>>>(
      gx, lin0_w, lin0_b, xg_a, lgx, l0lg_w, l0lg_b, xl_a,
      g_ea, g_w1, g_b1, h_g, lg_ea, lg_w1, lg_b1, h_l,
      g_w2, g_b2, bp_g, lg_w2, lg_b2, bp_l, g_root, rp_g, lg_root, rp_l,
      B0, B1, B2, B3, B4, B5, B6, B7, B8,
      NG, NLG, EG, ELG, cnt_g, NZ, pool_g, sctr);
  const int nhg = (EG + 255) / 256, nhl = (ELG + 255) / 256;
  hist_kernel<<<nhg + nhl, 256, 0, stream>>>(g_ei, cnt_g, el_g, EG, nhg, lg_ei, cnt_l, el_l, ELG);

  // ---- fused 3-iteration loop (256 edges/block, 4 waves x 64 edges, 16KB-chunk LDS ring) ----
  const int nbg_m = (EG + 255) / 256, nbl_m = (ELG + 255) / 256;
  const int nbg_u = (NG + 127) / 128, nbl_u = (NLG + 127) / 128;
  u16 *xgc = xg_a, *xgn = xg_b, *xlc = xl_a, *xln = xl_b;
  for (int it = 0; it < 3; ++it) {
    msg_gemm_kernel<<<nbg_m + nbl_m, 256, 0, stream>>>(
        xgc, h_g, bp_g, g_ei, msg_g, EG, nbg_m,
        xlc, h_l, bp_l, lg_ei, msg_l, ELG);
    update_kernel<<<nbg_u + nbl_u, 256, 0, stream>>>(
        xgc, msg_g, cnt_g, el_g, rp_g, g_bias, xgn, NG, nbg_u,
        xlc, msg_l, cnt_l, el_l, rp_l, lg_bias, xln, NLG,
        pool_g, pool_l, (it == 2) ? 1 : 0);
    u16* tmp = xgc; xgc = xgn; xgn = tmp;
    tmp = xlc; xlc = xln; xln = tmp;
  }

  // ---- head: 24 blocks, pool already fused into update it=2 (stream order) ----
  head_kernel<<<24, 256, 0, stream>>>(
      pool_g, pool_l, adduct, bott_w, bott_b, lin1_w, lin1_b, lin2_w, lin2_b,
      h0, h1, sctr, (float*)d_out);
}